// Round 12
// baseline (468.672 us; speedup 1.0000x reference)
//
#include <hip/hip_runtime.h>
#include <hip/hip_bf16.h>
#include <math.h>

#define BS 16
#define C 192
#define H 120
#define W 120
#define HW 14400
#define AN 36
#define MID 18
#define CPG 64
#define EPS 1e-5f
#define SPX 128
#define BPS 200
#define NWQ 13824   // 3g * 2cc * 9tap * 4hi * 64co units (16B each)
#define XROWS 122
#define XCOLS 132
#define OPX 64      // k_out pixels per block
#define WST 72      // k_out w LDS stride (shorts)
#define NBLK 113    // score blocks per batch
#define TST 132     // transpose-tile stride (shorts)

typedef __attribute__((ext_vector_type(8))) short s16x8;
typedef __attribute__((ext_vector_type(4))) float f32x4;
typedef __attribute__((ext_vector_type(4))) unsigned short u16x4;

static __device__ __forceinline__ short f2bf(float f) {
    union { float f; unsigned u; } v; v.f = f;
    unsigned r = (v.u + 0x7FFF + ((v.u >> 16) & 1)) >> 16;
    return (short)r;
}
static __device__ __forceinline__ float bf2f(unsigned short u) {
    union { unsigned u; float f; } v; v.u = ((unsigned)u) << 16;
    return v.f;
}
static __device__ __forceinline__ s16x8 cvt8(float4 f0, float4 f1) {
    s16x8 v;
    v[0] = f2bf(f0.x); v[1] = f2bf(f0.y); v[2] = f2bf(f0.z); v[3] = f2bf(f0.w);
    v[4] = f2bf(f1.x); v[5] = f2bf(f1.y); v[6] = f2bf(f1.z); v[7] = f2bf(f1.w);
    return v;
}

// ------- fold BN1 into key_w, bf16, B-fragment layout -------
__global__ __launch_bounds__(256) void k_wfold(const float* __restrict__ kw,
                                               const float* __restrict__ g1,
                                               const float* __restrict__ v1,
                                               unsigned short* __restrict__ Wq) {
    int u = blockIdx.x * 256 + threadIdx.x;
    if (u >= NWQ) return;
    int gc = u / 2304, rem = u - gc * 2304;
    int g = gc >> 1, cc = gc & 1;
    int th = rem >> 6, co = rem & 63;
    int tap = th >> 2, hi = th & 3;
    int cog = g * 64 + co;
    float inv = g1[cog] * rsqrtf(v1[cog] + EPS);
    const float* wp = kw + ((size_t)cog * 64 + cc * 32 + hi * 8) * 9 + tap;
    s16x8 v;
    #pragma unroll
    for (int e = 0; e < 8; ++e) v[e] = f2bf(wp[e * 9] * inv);
    *(s16x8*)&Wq[(size_t)u * 8] = v;
}

// ---------------- pool6: x f32 (b,c,120,120) -> P (b,c,36) ----------------
__global__ __launch_bounds__(256) void k_pool(const float* __restrict__ x,
                                              float* __restrict__ P) {
    int bc = blockIdx.x;
    const float* xp = x + (size_t)bc * HW;
    __shared__ float acc[AN];
    int tid = threadIdx.x;
    if (tid < AN) acc[tid] = 0.f;
    __syncthreads();
    for (int s = tid; s < 720; s += 256) {
        int y = s / 6, xs = s % 6;
        const float4* p4 = (const float4*)(xp + y * W + xs * 20);
        float sum = 0.f;
        #pragma unroll
        for (int i = 0; i < 5; ++i) {
            float4 v = p4[i];
            sum += v.x + v.y + v.z + v.w;
        }
        atomicAdd(&acc[(y / 20) * 6 + xs], sum);
    }
    __syncthreads();
    if (tid < AN) P[(size_t)bc * AN + tid] = acc[tid] * (1.f / 400.f);
}

// ------- Vb[b][cc][64] bf16 = val_w @ pooled (a>=36 zero-padded) -------
__global__ __launch_bounds__(256) void k_val(const float* __restrict__ valw,
                                             const float* __restrict__ P,
                                             unsigned short* __restrict__ Vb) {
    int b = blockIdx.x;
    __shared__ float Pl[C * AN];
    int tid = threadIdx.x;
    for (int i = tid; i < C * AN; i += 256) Pl[i] = P[(size_t)b * C * AN + i];
    __syncthreads();
    for (int o = tid; o < C * 8; o += 256) {
        int cc = o >> 3, a8 = o & 7;
        s16x8 vv = {0, 0, 0, 0, 0, 0, 0, 0};
        #pragma unroll
        for (int j = 0; j < 8; ++j) {
            int a = a8 * 8 + j;
            if (a < AN) {
                float s = 0.f;
                for (int k = 0; k < C; ++k) s += valw[cc * C + k] * Pl[k * AN + a];
                vv[j] = f2bf(s);
            }
        }
        *(s16x8*)&Vb[((size_t)b * C + cc) * 64 + a8 * 8] = vv;
    }
}

// ------- xTp builder + fused S2n (q_attn) compute -------
// per (y,b): stage x row bf16 in LDS, write padded xTp row, then
// S2[a,px] = agent . x  via MFMA from the same LDS, per-pixel softmax, store.
__global__ __launch_bounds__(256) void k_xt2(const float* __restrict__ x,
                                             const float* __restrict__ Pp,
                                             unsigned short* __restrict__ xTp,
                                             unsigned short* __restrict__ S2n) {
    int y = blockIdx.x, b = blockIdx.y;
    int t = threadIdx.x;
    __shared__ unsigned short L[128 * 200];
    int w = t >> 6, l = t & 63, lr = l & 15, hi = l >> 4;

    // agent A-fragments (rows 36..47 zero)
    s16x8 afr[3][6];
    if (S2n) {
        const float* ab = Pp + (size_t)b * (C * AN);
        #pragma unroll
        for (int mt = 0; mt < 3; ++mt) {
            int row = mt * 16 + lr;
            #pragma unroll
            for (int kc = 0; kc < 6; ++kc) {
                s16x8 v = {0, 0, 0, 0, 0, 0, 0, 0};
                if (row < AN) {
                    const float4* ap = (const float4*)(ab + row * C + kc * 32 + hi * 8);
                    v = cvt8(ap[0], ap[1]);
                }
                afr[mt][kc] = v;
            }
        }
    }

    for (int u = t; u < 24 * 120; u += 256) {
        int oc = u / 120, px = u - oc * 120;
        const float* xp = x + ((size_t)b * C + oc * 8) * HW + y * W + px;
        s16x8 v;
        #pragma unroll
        for (int j = 0; j < 8; ++j) v[j] = f2bf(xp[(size_t)j * HW]);
        *(s16x8*)&L[px * 200 + oc * 8] = v;
    }
    // zero pad rows 120..127 (keeps MFMA B-frags defined)
    for (int u = t; u < 8 * 24; u += 256) {
        int row = 120 + u / 24, oc = u - (u / 24) * 24;
        s16x8 z = {0, 0, 0, 0, 0, 0, 0, 0};
        *(s16x8*)&L[row * 200 + oc * 8] = z;
    }
    __syncthreads();
    // padded xTp row
    for (int u = t; u < 24 * XCOLS; u += 256) {
        int oc = u / XCOLS, p = u - oc * XCOLS;
        int px = p - 1;
        s16x8 v = {0, 0, 0, 0, 0, 0, 0, 0};
        if (px >= 0 && px < 120) v = *(const s16x8*)&L[px * 200 + oc * 8];
        *(s16x8*)&xTp[(((size_t)(b * 24 + oc)) * XROWS + (y + 1)) * XCOLS * 8 + p * 8] = v;
    }
    if (y == 0 || y == H - 1) {
        int r = (y == 0) ? 0 : XROWS - 1;
        s16x8 z = {0, 0, 0, 0, 0, 0, 0, 0};
        for (int u = t; u < 24 * XCOLS; u += 256) {
            int oc = u / XCOLS, p = u - oc * XCOLS;
            *(s16x8*)&xTp[(((size_t)(b * 24 + oc)) * XROWS + r) * XCOLS * 8 + p * 8] = z;
        }
    }
    if (!S2n) return;

    // S2 GEMM from L
    f32x4 acc[3][2];
    #pragma unroll
    for (int mt = 0; mt < 3; ++mt)
        #pragma unroll
        for (int pt = 0; pt < 2; ++pt)
            acc[mt][pt] = (f32x4){0.f, 0.f, 0.f, 0.f};
    #pragma unroll
    for (int kc = 0; kc < 6; ++kc) {
        s16x8 bf[2];
        #pragma unroll
        for (int pt = 0; pt < 2; ++pt) {
            int px = (w * 2 + pt) * 16 + lr;
            bf[pt] = *(const s16x8*)&L[px * 200 + kc * 32 + hi * 8];
        }
        #pragma unroll
        for (int mt = 0; mt < 3; ++mt)
            #pragma unroll
            for (int pt = 0; pt < 2; ++pt)
                acc[mt][pt] = __builtin_amdgcn_mfma_f32_16x16x32_bf16(
                    afr[mt][kc], bf[pt], acc[mt][pt], 0, 0, 0);
    }
    // per-pixel softmax over a, normalized in-register
    #pragma unroll
    for (int pt = 0; pt < 2; ++pt) {
        float pmax = -1e30f;
        #pragma unroll
        for (int mt = 0; mt < 3; ++mt)
            #pragma unroll
            for (int r = 0; r < 4; ++r) {
                int a = mt * 16 + hi * 4 + r;
                if (a < AN) pmax = fmaxf(pmax, acc[mt][pt][r]);
            }
        pmax = fmaxf(pmax, __shfl_xor(pmax, 16, 64));
        pmax = fmaxf(pmax, __shfl_xor(pmax, 32, 64));
        float psum = 0.f;
        #pragma unroll
        for (int mt = 0; mt < 3; ++mt)
            #pragma unroll
            for (int r = 0; r < 4; ++r) {
                int a = mt * 16 + hi * 4 + r;
                float e = (a < AN) ? __expf(acc[mt][pt][r] - pmax) : 0.f;
                acc[mt][pt][r] = e;
                psum += e;
            }
        psum += __shfl_xor(psum, 16, 64);
        psum += __shfl_xor(psum, 32, 64);
        float rs = 1.f / psum;
        #pragma unroll
        for (int mt = 0; mt < 3; ++mt)
            #pragma unroll
            for (int r = 0; r < 4; ++r)
                acc[mt][pt][r] *= rs;
    }
    __syncthreads();      // done reading L; reuse as transpose tile
    short* T = (short*)L;
    #pragma unroll
    for (int mt = 0; mt < 3; ++mt)
        #pragma unroll
        for (int pt = 0; pt < 2; ++pt)
            #pragma unroll
            for (int r = 0; r < 4; ++r)
                T[(mt * 16 + hi * 4 + r) * TST + (w * 2 + pt) * 16 + lr] =
                    f2bf(acc[mt][pt][r]);
    __syncthreads();
    unsigned short* dst = S2n + (size_t)b * AN * HW + y * 120;
    for (int u = t; u < AN * 15; u += 256) {
        int a = u / 15, i = u - a * 15;
        *(s16x8*)&dst[(size_t)a * HW + i * 8] = *(s16x8*)&T[a * TST + i * 8];
    }
}

// ------------- grouped 3x3 conv + BN1 + ReLU, implicit-GEMM MFMA -------------
__global__ __launch_bounds__(256, 4) void k_conv_mfma(
        const unsigned short* __restrict__ xTp, const unsigned short* __restrict__ Wq,
        const float* __restrict__ g1, const float* __restrict__ b1,
        const float* __restrict__ m1, const float* __restrict__ v1,
        float* __restrict__ k1f, unsigned short* __restrict__ k1b, int writeF32) {
    int yp = blockIdx.x, g = blockIdx.y, b = blockIdx.z;
    int y0 = yp * 2;
    int t = threadIdx.x;
    __shared__ short xl[(2048 + 2) * 8];

    int w = t >> 6, l = t & 63, lr = l & 15, hi = l >> 4;
    int ry = w >> 1, xh = w & 1;
    f32x4 acc[4][4];
    #pragma unroll
    for (int mt = 0; mt < 4; ++mt)
        #pragma unroll
        for (int nt = 0; nt < 4; ++nt)
            acc[mt][nt] = (f32x4){0.f, 0.f, 0.f, 0.f};

    for (int cc = 0; cc < 2; ++cc) {
        if (cc) __syncthreads();
        const unsigned short* xbase =
            xTp + ((size_t)((b * 24 + g * 8 + cc * 4) * XROWS) + y0) * XCOLS * 8;
        #pragma unroll
        for (int k = 0; k < 8; ++k) {
            int u = t + 256 * k;
            int run = u >> 7, p = u & 127;
            int oct = run >> 2, r = run & 3;
            s16x8 v = *(const s16x8*)&xbase[((size_t)(oct * XROWS + r)) * XCOLS * 8 + p * 8];
            *(s16x8*)&xl[u * 8] = v;
        }
        __syncthreads();
        const s16x8* wq = (const s16x8*)Wq + (size_t)(g * 2 + cc) * 2304;
        s16x8 Bn[4];
        #pragma unroll
        for (int nt = 0; nt < 4; ++nt) Bn[nt] = wq[hi * 64 + nt * 16 + lr];
        #pragma unroll
        for (int tap = 0; tap < 9; ++tap) {
            int ky = tap / 3, kx = tap % 3;
            s16x8 Bc[4];
            #pragma unroll
            for (int nt = 0; nt < 4; ++nt) Bc[nt] = Bn[nt];
            if (tap < 8) {
                #pragma unroll
                for (int nt = 0; nt < 4; ++nt)
                    Bn[nt] = wq[((tap + 1) * 4 + hi) * 64 + nt * 16 + lr];
            }
            s16x8 A[4];
            #pragma unroll
            for (int mt = 0; mt < 4; ++mt) {
                int col = xh * 64 + mt * 16 + lr + kx;
                A[mt] = *(const s16x8*)&xl[((hi * 4 + ry + ky) * 128 + col) * 8];
            }
            #pragma unroll
            for (int mt = 0; mt < 4; ++mt)
                #pragma unroll
                for (int nt = 0; nt < 4; ++nt)
                    acc[mt][nt] = __builtin_amdgcn_mfma_f32_16x16x32_bf16(
                        A[mt], Bc[nt], acc[mt][nt], 0, 0, 0);
        }
    }
    int y = y0 + ry;
    #pragma unroll
    for (int nt = 0; nt < 4; ++nt) {
        int cog = g * CPG + nt * 16 + lr;
        float inv = g1[cog] * rsqrtf(v1[cog] + EPS);
        float beta = b1[cog] - m1[cog] * inv;
        #pragma unroll
        for (int mt = 0; mt < 4; ++mt) {
            int xcol = xh * 64 + mt * 16 + hi * 4;
            if (xcol >= 120) continue;
            float r0 = fmaxf(acc[mt][nt][0] + beta, 0.f);
            float r1 = fmaxf(acc[mt][nt][1] + beta, 0.f);
            float r2 = fmaxf(acc[mt][nt][2] + beta, 0.f);
            float r3 = fmaxf(acc[mt][nt][3] + beta, 0.f);
            size_t base = ((size_t)(b * C + cog)) * HW + y * W + xcol;
            if (writeF32) {
                *(float4*)&k1f[base] = make_float4(r0, r1, r2, r3);
            } else {
                u16x4 q;
                q[0] = (unsigned short)f2bf(r0); q[1] = (unsigned short)f2bf(r1);
                q[2] = (unsigned short)f2bf(r2); q[3] = (unsigned short)f2bf(r3);
                *(u16x4*)&k1b[base] = q;
            }
        }
    }
}

// ------- scores via MFMA: S1b = bf16 logits + block softmax partials.
//         (S2 only in fallback tier, staged from f32 x.) -------
__global__ __launch_bounds__(256, 3) void k_scores_mfma(
        const float* __restrict__ Pp, const float* __restrict__ k1f,
        const unsigned short* __restrict__ k1b, const float* __restrict__ x,
        unsigned short* __restrict__ S1b, unsigned short* __restrict__ S2n,
        float2* __restrict__ PS, int doS2) {
    int b = blockIdx.y;
    int bx = blockIdx.x;
    int n0 = bx * SPX;
    int t = threadIdx.x;
    int w = t >> 6, l = t & 63, lr = l & 15, hi = l >> 4;
    __shared__ short Bp[SPX * BPS];
    __shared__ float2 Ls[4][40];
    short* T = Bp;

    s16x8 afr[3][6];
    const float* ab = Pp + (size_t)b * (C * AN);
    #pragma unroll
    for (int mt = 0; mt < 3; ++mt) {
        int row = mt * 16 + lr;
        #pragma unroll
        for (int kc = 0; kc < 6; ++kc) {
            s16x8 v = {0, 0, 0, 0, 0, 0, 0, 0};
            if (row < AN) {
                const float4* ap = (const float4*)(ab + row * C + kc * 32 + hi * 8);
                v = cvt8(ap[0], ap[1]);
            }
            afr[mt][kc] = v;
        }
    }

    int npass = doS2 ? 2 : 1;
    #pragma unroll 1
    for (int s = 0; s < npass; ++s) {
        __syncthreads();
        if (s == 0 && k1b) {
            const unsigned short* src = k1b + (size_t)b * C * HW + (size_t)n0 * C;
            for (int i = t; i < SPX * 24; i += 256) {
                int row = i / 24, o = i - row * 24;
                s16x8 v = {0, 0, 0, 0, 0, 0, 0, 0};
                if (n0 + row < HW) v = *(const s16x8*)&src[row * C + o * 8];
                *(s16x8*)&Bp[row * BPS + o * 8] = v;
            }
        } else {
            const float* sf = (s == 0) ? k1f : x;
            const float4* src = (const float4*)(sf + (size_t)b * C * HW + (size_t)n0 * C);
            for (int i = t; i < SPX * 24; i += 256) {
                int row = i / 24, c8 = (i - row * 24) * 8;
                s16x8 v = {0, 0, 0, 0, 0, 0, 0, 0};
                if (n0 + row < HW)
                    v = cvt8(src[row * 48 + c8 / 4], src[row * 48 + c8 / 4 + 1]);
                *(s16x8*)&Bp[row * BPS + c8] = v;
            }
        }
        __syncthreads();
        f32x4 acc[3][2];
        #pragma unroll
        for (int mt = 0; mt < 3; ++mt)
            #pragma unroll
            for (int pt = 0; pt < 2; ++pt)
                acc[mt][pt] = (f32x4){0.f, 0.f, 0.f, 0.f};
        #pragma unroll
        for (int kc = 0; kc < 6; ++kc) {
            s16x8 bf[2];
            #pragma unroll
            for (int pt = 0; pt < 2; ++pt) {
                int px = (w * 2 + pt) * 16 + lr;
                bf[pt] = *(const s16x8*)&Bp[px * BPS + kc * 32 + hi * 8];
            }
            #pragma unroll
            for (int mt = 0; mt < 3; ++mt)
                #pragma unroll
                for (int pt = 0; pt < 2; ++pt)
                    acc[mt][pt] = __builtin_amdgcn_mfma_f32_16x16x32_bf16(
                        afr[mt][kc], bf[pt], acc[mt][pt], 0, 0, 0);
        }
        if (s == 0) {
            bool ok0 = (n0 + (w * 2) * 16 + lr) < HW;
            bool ok1 = (n0 + (w * 2 + 1) * 16 + lr) < HW;
            #pragma unroll
            for (int mt = 0; mt < 3; ++mt)
                #pragma unroll
                for (int r = 0; r < 4; ++r) {
                    float v0 = ok0 ? acc[mt][0][r] : -1e30f;
                    float v1 = ok1 ? acc[mt][1][r] : -1e30f;
                    float m = fmaxf(v0, v1);
                    #pragma unroll
                    for (int mk = 1; mk <= 8; mk <<= 1)
                        m = fmaxf(m, __shfl_xor(m, mk, 64));
                    float e = (ok0 ? __expf(v0 - m) : 0.f) + (ok1 ? __expf(v1 - m) : 0.f);
                    #pragma unroll
                    for (int mk = 1; mk <= 8; mk <<= 1)
                        e += __shfl_xor(e, mk, 64);
                    int a = mt * 16 + hi * 4 + r;
                    if (lr == 0 && a < AN) Ls[w][a] = make_float2(m, e);
                }
            __syncthreads();
            #pragma unroll
            for (int mt = 0; mt < 3; ++mt)
                #pragma unroll
                for (int pt = 0; pt < 2; ++pt)
                    #pragma unroll
                    for (int r = 0; r < 4; ++r)
                        T[(mt * 16 + hi * 4 + r) * TST + (w * 2 + pt) * 16 + lr] =
                            f2bf(acc[mt][pt][r]);
            __syncthreads();
            unsigned short* dst = S1b + (size_t)b * AN * HW + n0;
            for (int u = t; u < AN * 16; u += 256) {
                int a = u >> 4, i = u & 15;
                if (n0 + i * 8 < HW)
                    *(s16x8*)&dst[(size_t)a * HW + i * 8] = *(s16x8*)&T[a * TST + i * 8];
            }
        } else {
            #pragma unroll
            for (int pt = 0; pt < 2; ++pt) {
                float pmax = -1e30f;
                #pragma unroll
                for (int mt = 0; mt < 3; ++mt)
                    #pragma unroll
                    for (int r = 0; r < 4; ++r) {
                        int a = mt * 16 + hi * 4 + r;
                        if (a < AN) pmax = fmaxf(pmax, acc[mt][pt][r]);
                    }
                pmax = fmaxf(pmax, __shfl_xor(pmax, 16, 64));
                pmax = fmaxf(pmax, __shfl_xor(pmax, 32, 64));
                float psum = 0.f;
                #pragma unroll
                for (int mt = 0; mt < 3; ++mt)
                    #pragma unroll
                    for (int r = 0; r < 4; ++r) {
                        int a = mt * 16 + hi * 4 + r;
                        float e = (a < AN) ? __expf(acc[mt][pt][r] - pmax) : 0.f;
                        acc[mt][pt][r] = e;
                        psum += e;
                    }
                psum += __shfl_xor(psum, 16, 64);
                psum += __shfl_xor(psum, 32, 64);
                float rs = 1.f / psum;
                #pragma unroll
                for (int mt = 0; mt < 3; ++mt)
                    #pragma unroll
                    for (int r = 0; r < 4; ++r)
                        acc[mt][pt][r] *= rs;
            }
            __syncthreads();
            #pragma unroll
            for (int mt = 0; mt < 3; ++mt)
                #pragma unroll
                for (int pt = 0; pt < 2; ++pt)
                    #pragma unroll
                    for (int r = 0; r < 4; ++r)
                        T[(mt * 16 + hi * 4 + r) * TST + (w * 2 + pt) * 16 + lr] =
                            f2bf(acc[mt][pt][r]);
            __syncthreads();
            unsigned short* dst = S2n + (size_t)b * AN * HW + n0;
            for (int u = t; u < AN * 16; u += 256) {
                int a = u >> 4, i = u & 15;
                if (n0 + i * 8 < HW)
                    *(s16x8*)&dst[(size_t)a * HW + i * 8] = *(s16x8*)&T[a * TST + i * 8];
            }
        }
    }
    __syncthreads();
    if (t < AN) {
        float m = -1e30f, ssum = 0.f;
        #pragma unroll
        for (int wv = 0; wv < 4; ++wv) {
            float2 p = Ls[wv][t];
            float mn = fmaxf(m, p.x);
            ssum = ssum * __expf(m - mn) + p.y * __expf(p.x - mn);
            m = mn;
        }
        PS[((size_t)b * AN + t) * NBLK + bx] = make_float2(m, ssum);
    }
}

// ------- reduce per-block partials -> row stats (max, 1/sum) -------
__global__ __launch_bounds__(128) void k_redstats(const float2* __restrict__ PS,
                                                  float* __restrict__ stats) {
    int row = blockIdx.x;
    int t = threadIdx.x;
    float m = -1e30f, s = 0.f;
    for (int i = t; i < NBLK; i += 128) {
        float2 p = PS[(size_t)row * NBLK + i];
        float mn = fmaxf(m, p.x);
        s = s * __expf(m - mn) + p.y * __expf(p.x - mn);
        m = mn;
    }
    #pragma unroll
    for (int off = 32; off > 0; off >>= 1) {
        float om = __shfl_down(m, off, 64);
        float os = __shfl_down(s, off, 64);
        float mn = fmaxf(m, om);
        s = s * __expf(m - mn) + os * __expf(om - mn);
        m = mn;
    }
    __shared__ float2 red[2];
    if ((t & 63) == 0) red[t >> 6] = make_float2(m, s);
    __syncthreads();
    if (t == 0) {
        float2 a = red[0], bb = red[1];
        float mn = fmaxf(a.x, bb.x);
        float ss = a.y * __expf(a.x - mn) + bb.y * __expf(bb.x - mn);
        stats[row] = mn;
        stats[576 + row] = 1.f / ss;
    }
}

// ------- fused: softmax(S1b) via stats, pre-normalized S2n, conv1+BN2+ReLU, conv2 -------
__global__ __launch_bounds__(256) void k_fuse(const unsigned short* __restrict__ S1b,
                                              const float* __restrict__ stats,
                                              const unsigned short* __restrict__ S2n,
                                              const float* __restrict__ w1,
                                              const float* __restrict__ g2,
                                              const float* __restrict__ b2,
                                              const float* __restrict__ m2,
                                              const float* __restrict__ v2,
                                              const float* __restrict__ w2,
                                              const float* __restrict__ bias2,
                                              unsigned short* __restrict__ AMb) {
    int b = blockIdx.y;
    int tid = threadIdx.x;
    int N = blockIdx.x * 256 + tid;
    __shared__ float W1f[MID * 72];
    __shared__ float b1f[MID];
    __shared__ float W2m[AN * MID];
    __shared__ float b2m[AN];
    __shared__ float sm_m[AN], sm_ri[AN];
    for (int i = tid; i < MID * 72; i += 256) {
        int m = i / 72;
        W1f[i] = w1[i] * (g2[m] * rsqrtf(v2[m] + EPS));
    }
    if (tid < MID) {
        float inv = g2[tid] * rsqrtf(v2[tid] + EPS);
        b1f[tid] = b2[tid] - m2[tid] * inv;
    }
    for (int i = tid; i < AN * MID; i += 256) {
        int a = i / MID, m = i % MID;
        float s = 0.f;
        #pragma unroll
        for (int k = 0; k < 9; ++k) s += w2[(a * 9 + k) * MID + m];
        W2m[i] = s * (1.f / 9.f);
    }
    if (tid < AN) {
        float s = 0.f;
        #pragma unroll
        for (int k = 0; k < 9; ++k) s += bias2[tid * 9 + k];
        b2m[tid] = s * (1.f / 9.f);
        sm_m[tid] = stats[b * AN + tid];
        sm_ri[tid] = stats[576 + b * AN + tid];
    }
    __syncthreads();
    if (N >= HW) return;
    float yv[72];
    const unsigned short* a1p = S1b + (size_t)b * AN * HW + N;
    #pragma unroll
    for (int j = 0; j < AN; ++j)
        yv[j] = __expf(bf2f(a1p[(size_t)j * HW]) - sm_m[j]) * sm_ri[j];
    const unsigned short* s2p = S2n + (size_t)b * AN * HW + N;
    #pragma unroll
    for (int j = 0; j < AN; ++j) yv[AN + j] = bf2f(s2p[(size_t)j * HW]);
    float t[MID];
    #pragma unroll
    for (int m = 0; m < MID; ++m) {
        float a = b1f[m];
        #pragma unroll
        for (int j = 0; j < 72; ++j) a += W1f[m * 72 + j] * yv[j];
        t[m] = a > 0.f ? a : 0.f;
    }
    unsigned short* amp = AMb + (size_t)b * AN * HW + N;
    #pragma unroll
    for (int a = 0; a < AN; ++a) {
        float acc = b2m[a];
        #pragma unroll
        for (int m = 0; m < MID; ++m) acc += W2m[a * MID + m] * t[m];
        amp[(size_t)a * HW] = (unsigned short)f2bf(acc);
    }
}

// ------- out via MFMA: out[cc][n] = sum_a softmax36(AMb window)[a]*Vb[cc][a] + k1 -------
__global__ __launch_bounds__(256) void k_out_mfma(const unsigned short* __restrict__ AMb,
                                                  const unsigned short* __restrict__ Vb,
                                                  const unsigned short* __restrict__ k1b,
                                                  float* __restrict__ outp) {
    int b = blockIdx.y;
    int N0 = blockIdx.x * OPX;
    int t = threadIdx.x;
    __shared__ float smemf[4 * 1088];
    short* wl = (short*)smemf;

    {
        int p = t >> 2, q = t & 3;
        int N = N0 + p;
        int a = N / 400;
        int n0w = (N - a * 400) * AN;
        const unsigned short* amp = AMb + ((size_t)b * AN + a) * HW + n0w;
        const int qoff = (q == 0) ? 0 : (q == 1) ? 12 : (q == 2) ? 20 : 32;
        const int qn4 = (q == 0) ? 3 : (q == 1) ? 2 : (q == 2) ? 3 : 1;
        float vals[12];
        const u16x4* ap = (const u16x4*)(amp + qoff);
        #pragma unroll
        for (int i = 0; i < 3; ++i) {
            if (i < qn4) {
                u16x4 v = ap[i];
                vals[i * 4 + 0] = bf2f(v[0]); vals[i * 4 + 1] = bf2f(v[1]);
                vals[i * 4 + 2] = bf2f(v[2]); vals[i * 4 + 3] = bf2f(v[3]);
            }
        }
        int cnt = qn4 * 4;
        float m = -1e30f;
        #pragma unroll
        for (int i = 0; i < 12; ++i) if (i < cnt) m = fmaxf(m, vals[i]);
        m = fmaxf(m, __shfl_xor(m, 1, 64));
        m = fmaxf(m, __shfl_xor(m, 2, 64));
        float s = 0.f;
        #pragma unroll
        for (int i = 0; i < 12; ++i)
            if (i < cnt) { vals[i] = __expf(vals[i] - m); s += vals[i]; }
        s += __shfl_xor(s, 1, 64);
        s += __shfl_xor(s, 2, 64);
        float rs = 1.f / s;
        #pragma unroll
        for (int i = 0; i < 12; ++i)
            if (i < cnt) wl[p * WST + qoff + i] = f2bf(vals[i] * rs);
        if (q == 3) {
            #pragma unroll
            for (int i = 36; i < 64; ++i) wl[p * WST + i] = 0;
        }
    }
    __syncthreads();

    int w = t >> 6, l = t & 63, lr = l & 15, hi = l >> 4;
    int cc0 = w * 48;
    const s16x8* vb = (const s16x8*)(Vb + (size_t)b * C * 64);
    s16x8 Af[3][2];
    #pragma unroll
    for (int mt = 0; mt < 3; ++mt)
        #pragma unroll
        for (int ch = 0; ch < 2; ++ch)
            Af[mt][ch] = vb[(cc0 + mt * 16 + lr) * 8 + ch * 4 + hi];
    f32x4 acc[3][4];
    #pragma unroll
    for (int mt = 0; mt < 3; ++mt)
        #pragma unroll
        for (int pt = 0; pt < 4; ++pt)
            acc[mt][pt] = (f32x4){0.f, 0.f, 0.f, 0.f};
    #pragma unroll
    for (int pt = 0; pt < 4; ++pt) {
        s16x8 Bf[2];
        #pragma unroll
        for (int ch = 0; ch < 2; ++ch)
            Bf[ch] = *(const s16x8*)&wl[(pt * 16 + lr) * WST + ch * 32 + hi * 8];
        #pragma unroll
        for (int ch = 0; ch < 2; ++ch)
            #pragma unroll
            for (int mt = 0; mt < 3; ++mt)
                acc[mt][pt] = __builtin_amdgcn_mfma_f32_16x16x32_bf16(
                    Af[mt][ch], Bf[ch], acc[mt][pt], 0, 0, 0);
    }
    __syncthreads();

    float* T = smemf + (size_t)w * 1088;
    int px4 = (l & 15) * 4;
    #pragma unroll
    for (int mt = 0; mt < 3; ++mt) {
        u16x4 kk[4];
        float4 rf[4];
        #pragma unroll
        for (int pass = 0; pass < 4; ++pass) {
            int ccr = pass * 4 + hi;
            int cc = cc0 + mt * 16 + ccr;
            size_t idx = ((size_t)(b * C + cc)) * HW + N0 + px4;
            if (k1b) kk[pass] = *(const u16x4*)&k1b[idx];
            else rf[pass] = *(float4*)&outp[idx];
        }
        #pragma unroll
        for (int pt = 0; pt < 4; ++pt)
            #pragma unroll
            for (int r = 0; r < 4; ++r)
                T[(hi * 4 + r) * 68 + pt * 16 + lr] = acc[mt][pt][r];
        #pragma unroll
        for (int pass = 0; pass < 4; ++pass) {
            int ccr = pass * 4 + hi;
            float4 vv = *(float4*)&T[ccr * 68 + px4];
            int cc = cc0 + mt * 16 + ccr;
            size_t idx = ((size_t)(b * C + cc)) * HW + N0 + px4;
            float4 res;
            if (k1b) res = make_float4(bf2f(kk[pass][0]), bf2f(kk[pass][1]),
                                       bf2f(kk[pass][2]), bf2f(kk[pass][3]));
            else res = rf[pass];
            vv.x += res.x; vv.y += res.y; vv.z += res.z; vv.w += res.w;
            *(float4*)&outp[idx] = vv;
        }
    }
}

extern "C" void kernel_launch(void* const* d_in, const int* in_sizes, int n_in,
                              void* d_out, int out_size, void* d_ws, size_t ws_size,
                              hipStream_t stream) {
    const float* x      = (const float*)d_in[0];
    const float* key_w  = (const float*)d_in[1];
    const float* bn1_g  = (const float*)d_in[2];
    const float* bn1_b  = (const float*)d_in[3];
    const float* bn1_m  = (const float*)d_in[4];
    const float* bn1_v  = (const float*)d_in[5];
    const float* val_w  = (const float*)d_in[6];
    const float* att_w1 = (const float*)d_in[7];
    const float* bn2_g  = (const float*)d_in[8];
    const float* bn2_b  = (const float*)d_in[9];
    const float* bn2_m  = (const float*)d_in[10];
    const float* bn2_v  = (const float*)d_in[11];
    const float* att_w2 = (const float*)d_in[12];
    const float* att_b2 = (const float*)d_in[13];
    float* out = (float*)d_out;

    unsigned char* base = (unsigned char*)d_ws;
    size_t off = 0;
    unsigned short* Wq = (unsigned short*)(base + off); off += 221184;
    unsigned short* Vb = (unsigned short*)(base + off); off += 393216;
    float* P  = (float*)(base + off); off += 442368;
    float* ST = (float*)(base + off); off += 4608;
    float2* PS = (float2*)(base + off); off += 520704;    // 576*113*8
    unsigned char* big = base + off;
    size_t nS2 = (size_t)BS * AN * HW * 2;                // 16,588,800
    size_t xtpBytes = (size_t)BS * 24 * XROWS * XCOLS * 16;  // 98,942,976
    unsigned short* S1b = (unsigned short*)big;
    unsigned short* S2n = (unsigned short*)(big + nS2);
    unsigned short* AMb = (unsigned short*)(big + 2 * nS2);
    off += xtpBytes;                                      // big region reservation
    size_t k1bBytes = (size_t)BS * C * HW * 2;            // 88,473,600
    unsigned short* k1b = nullptr;
    unsigned short* xTp = (unsigned short*)big;           // fallback alias
    int xtpSep = 0;
    if (ws_size >= off + k1bBytes) {
        k1b = (unsigned short*)(base + off); off += k1bBytes;
        if (ws_size >= off + xtpBytes) {
            xTp = (unsigned short*)(base + off); off += xtpBytes;
            xtpSep = 1;
        }
    }
    int writeF32 = (k1b == nullptr) ? 1 : 0;

    k_wfold<<<(NWQ + 255) / 256, 256, 0, stream>>>(key_w, bn1_g, bn1_v, Wq);
    k_pool<<<BS * C, 256, 0, stream>>>(x, P);
    k_val<<<BS, 256, 0, stream>>>(val_w, P, Vb);
    // full tier: xt2 computes S2n in-pass (xTp separate). fallback: skip S2 here.
    k_xt2<<<dim3(H, BS), 256, 0, stream>>>(x, P, xTp, xtpSep ? S2n : nullptr);
    k_conv_mfma<<<dim3(H / 2, 3, BS), 256, 0, stream>>>(
        xTp, Wq, bn1_g, bn1_b, bn1_m, bn1_v, out, k1b, writeF32);
    k_scores_mfma<<<dim3(NBLK, BS), 256, 0, stream>>>(
        P, out, k1b, x, S1b, S2n, PS, xtpSep ? 0 : 1);
    k_redstats<<<BS * AN, 128, 0, stream>>>(PS, ST);
    k_fuse<<<dim3((HW + 255) / 256, BS), 256, 0, stream>>>(
        S1b, ST, S2n, att_w1, bn2_g, bn2_b, bn2_m, bn2_v, att_w2, att_b2, AMb);
    k_out_mfma<<<dim3(HW / OPX, BS), 256, 0, stream>>>(AMb, Vb, k1b, out);
}

// Round 13
// 463.701 us; speedup vs baseline: 1.0107x; 1.0107x over previous
//
#include <hip/hip_runtime.h>
#include <hip/hip_bf16.h>
#include <math.h>

#define BS 16
#define C 192
#define H 120
#define W 120
#define HW 14400
#define AN 36
#define MID 18
#define CPG 64
#define EPS 1e-5f
#define SPX 128
#define BPS 200
#define NWQ 13824   // 3g * 2cc * 9tap * 4hi * 64co units (16B each)
#define XROWS 122
#define XCOLS 132
#define OPX 64      // k_out pixels per block
#define WST 72      // k_out w LDS stride (shorts)
#define NBLK 113    // score blocks per batch
#define TST 132     // transpose-tile stride (shorts)

typedef __attribute__((ext_vector_type(8))) short s16x8;
typedef __attribute__((ext_vector_type(4))) float f32x4;
typedef __attribute__((ext_vector_type(4))) unsigned short u16x4;

static __device__ __forceinline__ short f2bf(float f) {
    union { float f; unsigned u; } v; v.f = f;
    unsigned r = (v.u + 0x7FFF + ((v.u >> 16) & 1)) >> 16;
    return (short)r;
}
static __device__ __forceinline__ float bf2f(unsigned short u) {
    union { unsigned u; float f; } v; v.u = ((unsigned)u) << 16;
    return v.f;
}
static __device__ __forceinline__ s16x8 cvt8(float4 f0, float4 f1) {
    s16x8 v;
    v[0] = f2bf(f0.x); v[1] = f2bf(f0.y); v[2] = f2bf(f0.z); v[3] = f2bf(f0.w);
    v[4] = f2bf(f1.x); v[5] = f2bf(f1.y); v[6] = f2bf(f1.z); v[7] = f2bf(f1.w);
    return v;
}

// ------- fold BN1 into key_w, bf16, B-fragment layout -------
__global__ __launch_bounds__(256) void k_wfold(const float* __restrict__ kw,
                                               const float* __restrict__ g1,
                                               const float* __restrict__ v1,
                                               unsigned short* __restrict__ Wq) {
    int u = blockIdx.x * 256 + threadIdx.x;
    if (u >= NWQ) return;
    int gc = u / 2304, rem = u - gc * 2304;
    int g = gc >> 1, cc = gc & 1;
    int th = rem >> 6, co = rem & 63;
    int tap = th >> 2, hi = th & 3;
    int cog = g * 64 + co;
    float inv = g1[cog] * rsqrtf(v1[cog] + EPS);
    const float* wp = kw + ((size_t)cog * 64 + cc * 32 + hi * 8) * 9 + tap;
    s16x8 v;
    #pragma unroll
    for (int e = 0; e < 8; ++e) v[e] = f2bf(wp[e * 9] * inv);
    *(s16x8*)&Wq[(size_t)u * 8] = v;
}

// ------- xTp: x f32 [b,c,hw] -> bf16 [b][oct24][row 122][col 132][8], zero halo -------
__global__ __launch_bounds__(256) void k_xt(const float* __restrict__ x,
                                            unsigned short* __restrict__ xTp) {
    int y = blockIdx.x, b = blockIdx.y;
    int t = threadIdx.x;
    __shared__ unsigned short L[120 * 200];
    for (int u = t; u < 24 * 120; u += 256) {
        int oc = u / 120, px = u - oc * 120;
        const float* xp = x + ((size_t)b * C + oc * 8) * HW + y * W + px;
        s16x8 v;
        #pragma unroll
        for (int j = 0; j < 8; ++j) v[j] = f2bf(xp[(size_t)j * HW]);
        *(s16x8*)&L[px * 200 + oc * 8] = v;
    }
    __syncthreads();
    for (int u = t; u < 24 * XCOLS; u += 256) {
        int oc = u / XCOLS, p = u - oc * XCOLS;
        int px = p - 1;
        s16x8 v = {0, 0, 0, 0, 0, 0, 0, 0};
        if (px >= 0 && px < 120) v = *(const s16x8*)&L[px * 200 + oc * 8];
        *(s16x8*)&xTp[(((size_t)(b * 24 + oc)) * XROWS + (y + 1)) * XCOLS * 8 + p * 8] = v;
    }
    if (y == 0 || y == H - 1) {
        int r = (y == 0) ? 0 : XROWS - 1;
        s16x8 z = {0, 0, 0, 0, 0, 0, 0, 0};
        for (int u = t; u < 24 * XCOLS; u += 256) {
            int oc = u / XCOLS, p = u - oc * XCOLS;
            *(s16x8*)&xTp[(((size_t)(b * 24 + oc)) * XROWS + r) * XCOLS * 8 + p * 8] = z;
        }
    }
}

// ------- pool6 from bf16 xTp (L3-hot): P[b][c][36] f32 -------
__global__ __launch_bounds__(256) void k_pool_b(const unsigned short* __restrict__ xTp,
                                                float* __restrict__ P) {
    int oc = blockIdx.x, b = blockIdx.y;
    int t = threadIdx.x;
    __shared__ float Lp[240 * 24];
    const unsigned short* base =
        xTp + (((size_t)(b * 24 + oc)) * XROWS + 1) * XCOLS * 8 + 8;
    if (t < 240) {
        int y = t >> 1, h = t & 1;
        const unsigned short* row = base + (size_t)y * XCOLS * 8 + h * 60 * 8;
        float acc[3][8];
        #pragma unroll
        for (int qq = 0; qq < 3; ++qq)
            #pragma unroll
            for (int e = 0; e < 8; ++e) acc[qq][e] = 0.f;
        #pragma unroll
        for (int qq = 0; qq < 3; ++qq)
            for (int j = 0; j < 20; ++j) {
                s16x8 v = *(const s16x8*)&row[(qq * 20 + j) * 8];
                #pragma unroll
                for (int e = 0; e < 8; ++e) acc[qq][e] += bf2f((unsigned short)v[e]);
            }
        #pragma unroll
        for (int qq = 0; qq < 3; ++qq)
            #pragma unroll
            for (int e = 0; e < 8; ++e) Lp[t * 24 + qq * 8 + e] = acc[qq][e];
    }
    __syncthreads();
    if (t < 288) {
        int seg = t >> 3, e = t & 7;
        int yq = seg / 6, q = seg % 6;
        int h = q / 3, qq = q % 3;
        float s = 0.f;
        for (int j = 0; j < 20; ++j)
            s += Lp[((yq * 20 + j) * 2 + h) * 24 + qq * 8 + e];
        P[((size_t)b * C + oc * 8 + e) * AN + seg] = s * (1.f / 400.f);
    }
}

// ------- Vb[b][cc][64] bf16 = val_w @ pooled (a>=36 zero-padded) -------
__global__ __launch_bounds__(256) void k_val(const float* __restrict__ valw,
                                             const float* __restrict__ P,
                                             unsigned short* __restrict__ Vb) {
    int b = blockIdx.x;
    __shared__ float Pl[C * AN];
    int tid = threadIdx.x;
    for (int i = tid; i < C * AN; i += 256) Pl[i] = P[(size_t)b * C * AN + i];
    __syncthreads();
    for (int o = tid; o < C * 8; o += 256) {
        int cc = o >> 3, a8 = o & 7;
        s16x8 vv = {0, 0, 0, 0, 0, 0, 0, 0};
        #pragma unroll
        for (int j = 0; j < 8; ++j) {
            int a = a8 * 8 + j;
            if (a < AN) {
                float s = 0.f;
                for (int k = 0; k < C; ++k) s += valw[cc * C + k] * Pl[k * AN + a];
                vv[j] = f2bf(s);
            }
        }
        *(s16x8*)&Vb[((size_t)b * C + cc) * 64 + a8 * 8] = vv;
    }
}

// ------------- grouped 3x3 conv + BN1 + ReLU, implicit-GEMM MFMA -------------
__global__ __launch_bounds__(256, 4) void k_conv_mfma(
        const unsigned short* __restrict__ xTp, const unsigned short* __restrict__ Wq,
        const float* __restrict__ g1, const float* __restrict__ b1,
        const float* __restrict__ m1, const float* __restrict__ v1,
        float* __restrict__ k1f, unsigned short* __restrict__ k1b, int writeF32) {
    int yp = blockIdx.x, g = blockIdx.y, b = blockIdx.z;
    int y0 = yp * 2;
    int t = threadIdx.x;
    __shared__ short xl[(2048 + 2) * 8];

    int w = t >> 6, l = t & 63, lr = l & 15, hi = l >> 4;
    int ry = w >> 1, xh = w & 1;
    f32x4 acc[4][4];
    #pragma unroll
    for (int mt = 0; mt < 4; ++mt)
        #pragma unroll
        for (int nt = 0; nt < 4; ++nt)
            acc[mt][nt] = (f32x4){0.f, 0.f, 0.f, 0.f};

    for (int cc = 0; cc < 2; ++cc) {
        if (cc) __syncthreads();
        const unsigned short* xbase =
            xTp + ((size_t)((b * 24 + g * 8 + cc * 4) * XROWS) + y0) * XCOLS * 8;
        #pragma unroll
        for (int k = 0; k < 8; ++k) {
            int u = t + 256 * k;
            int run = u >> 7, p = u & 127;
            int oct = run >> 2, r = run & 3;
            s16x8 v = *(const s16x8*)&xbase[((size_t)(oct * XROWS + r)) * XCOLS * 8 + p * 8];
            *(s16x8*)&xl[u * 8] = v;
        }
        __syncthreads();
        const s16x8* wq = (const s16x8*)Wq + (size_t)(g * 2 + cc) * 2304;
        s16x8 Bn[4];
        #pragma unroll
        for (int nt = 0; nt < 4; ++nt) Bn[nt] = wq[hi * 64 + nt * 16 + lr];
        #pragma unroll
        for (int tap = 0; tap < 9; ++tap) {
            int ky = tap / 3, kx = tap % 3;
            s16x8 Bc[4];
            #pragma unroll
            for (int nt = 0; nt < 4; ++nt) Bc[nt] = Bn[nt];
            if (tap < 8) {
                #pragma unroll
                for (int nt = 0; nt < 4; ++nt)
                    Bn[nt] = wq[((tap + 1) * 4 + hi) * 64 + nt * 16 + lr];
            }
            s16x8 A[4];
            #pragma unroll
            for (int mt = 0; mt < 4; ++mt) {
                int col = xh * 64 + mt * 16 + lr + kx;
                A[mt] = *(const s16x8*)&xl[((hi * 4 + ry + ky) * 128 + col) * 8];
            }
            #pragma unroll
            for (int mt = 0; mt < 4; ++mt)
                #pragma unroll
                for (int nt = 0; nt < 4; ++nt)
                    acc[mt][nt] = __builtin_amdgcn_mfma_f32_16x16x32_bf16(
                        A[mt], Bc[nt], acc[mt][nt], 0, 0, 0);
        }
    }
    int y = y0 + ry;
    #pragma unroll
    for (int nt = 0; nt < 4; ++nt) {
        int cog = g * CPG + nt * 16 + lr;
        float inv = g1[cog] * rsqrtf(v1[cog] + EPS);
        float beta = b1[cog] - m1[cog] * inv;
        #pragma unroll
        for (int mt = 0; mt < 4; ++mt) {
            int xcol = xh * 64 + mt * 16 + hi * 4;
            if (xcol >= 120) continue;
            float r0 = fmaxf(acc[mt][nt][0] + beta, 0.f);
            float r1 = fmaxf(acc[mt][nt][1] + beta, 0.f);
            float r2 = fmaxf(acc[mt][nt][2] + beta, 0.f);
            float r3 = fmaxf(acc[mt][nt][3] + beta, 0.f);
            size_t base = ((size_t)(b * C + cog)) * HW + y * W + xcol;
            if (writeF32) {
                *(float4*)&k1f[base] = make_float4(r0, r1, r2, r3);
            } else {
                u16x4 q;
                q[0] = (unsigned short)f2bf(r0); q[1] = (unsigned short)f2bf(r1);
                q[2] = (unsigned short)f2bf(r2); q[3] = (unsigned short)f2bf(r3);
                *(u16x4*)&k1b[base] = q;
            }
        }
    }
}

// ------- scores via MFMA: S1b = bf16 logits + block softmax partials;
//         S2n = per-pixel-normalized bf16 q_attn. Coalesced stores via LDS transpose. -------
__global__ __launch_bounds__(256, 3) void k_scores_mfma(
        const float* __restrict__ Pp, const float* __restrict__ k1f,
        const unsigned short* __restrict__ k1b, const float* __restrict__ x,
        const unsigned short* __restrict__ xTp,
        unsigned short* __restrict__ S1b, unsigned short* __restrict__ S2n,
        float2* __restrict__ PS) {
    int b = blockIdx.y;
    int bx = blockIdx.x;
    int n0 = bx * SPX;
    int t = threadIdx.x;
    int w = t >> 6, l = t & 63, lr = l & 15, hi = l >> 4;
    __shared__ short Bp[SPX * BPS];
    __shared__ float2 Ls[4][40];
    short* T = Bp;   // transpose tile alias: [48][TST]

    s16x8 afr[3][6];
    const float* ab = Pp + (size_t)b * (C * AN);
    #pragma unroll
    for (int mt = 0; mt < 3; ++mt) {
        int row = mt * 16 + lr;
        #pragma unroll
        for (int kc = 0; kc < 6; ++kc) {
            s16x8 v = {0, 0, 0, 0, 0, 0, 0, 0};
            if (row < AN) {
                const float4* ap = (const float4*)(ab + row * C + kc * 32 + hi * 8);
                v = cvt8(ap[0], ap[1]);
            }
            afr[mt][kc] = v;
        }
    }

    #pragma unroll 1
    for (int s = 0; s < 2; ++s) {
        __syncthreads();
        if (s == 0 && k1b) {
            const unsigned short* src = k1b + (size_t)b * C * HW + (size_t)n0 * C;
            for (int i = t; i < SPX * 24; i += 256) {
                int row = i / 24, o = i - row * 24;
                s16x8 v = {0, 0, 0, 0, 0, 0, 0, 0};
                if (n0 + row < HW) v = *(const s16x8*)&src[row * C + o * 8];
                *(s16x8*)&Bp[row * BPS + o * 8] = v;
            }
        } else if (s == 1 && xTp) {
            for (int i = t; i < SPX * 24; i += 256) {
                int row = i / 24, oc = i - row * 24;
                int n = n0 + row;
                s16x8 v = {0, 0, 0, 0, 0, 0, 0, 0};
                if (n < HW) {
                    int yy = n / 120, xx = n - yy * 120;
                    v = *(const s16x8*)&xTp[(((size_t)(b * 24 + oc)) * XROWS + yy + 1) *
                                            XCOLS * 8 + (xx + 1) * 8];
                }
                *(s16x8*)&Bp[row * BPS + oc * 8] = v;
            }
        } else {
            const float* sf = (s == 0) ? k1f : x;
            const float4* src = (const float4*)(sf + (size_t)b * C * HW + (size_t)n0 * C);
            for (int i = t; i < SPX * 24; i += 256) {
                int row = i / 24, c8 = (i - row * 24) * 8;
                s16x8 v = {0, 0, 0, 0, 0, 0, 0, 0};
                if (n0 + row < HW)
                    v = cvt8(src[row * 48 + c8 / 4], src[row * 48 + c8 / 4 + 1]);
                *(s16x8*)&Bp[row * BPS + c8] = v;
            }
        }
        __syncthreads();
        f32x4 acc[3][2];
        #pragma unroll
        for (int mt = 0; mt < 3; ++mt)
            #pragma unroll
            for (int pt = 0; pt < 2; ++pt)
                acc[mt][pt] = (f32x4){0.f, 0.f, 0.f, 0.f};
        #pragma unroll
        for (int kc = 0; kc < 6; ++kc) {
            s16x8 bf[2];
            #pragma unroll
            for (int pt = 0; pt < 2; ++pt) {
                int px = (w * 2 + pt) * 16 + lr;
                bf[pt] = *(const s16x8*)&Bp[px * BPS + kc * 32 + hi * 8];
            }
            #pragma unroll
            for (int mt = 0; mt < 3; ++mt)
                #pragma unroll
                for (int pt = 0; pt < 2; ++pt)
                    acc[mt][pt] = __builtin_amdgcn_mfma_f32_16x16x32_bf16(
                        afr[mt][kc], bf[pt], acc[mt][pt], 0, 0, 0);
        }
        if (s == 0) {
            // per-block online-softmax partials per a-row (register/shuffle only)
            bool ok0 = (n0 + (w * 2) * 16 + lr) < HW;
            bool ok1 = (n0 + (w * 2 + 1) * 16 + lr) < HW;
            #pragma unroll
            for (int mt = 0; mt < 3; ++mt)
                #pragma unroll
                for (int r = 0; r < 4; ++r) {
                    float v0 = ok0 ? acc[mt][0][r] : -1e30f;
                    float v1 = ok1 ? acc[mt][1][r] : -1e30f;
                    float m = fmaxf(v0, v1);
                    #pragma unroll
                    for (int mk = 1; mk <= 8; mk <<= 1)
                        m = fmaxf(m, __shfl_xor(m, mk, 64));
                    float e = (ok0 ? __expf(v0 - m) : 0.f) + (ok1 ? __expf(v1 - m) : 0.f);
                    #pragma unroll
                    for (int mk = 1; mk <= 8; mk <<= 1)
                        e += __shfl_xor(e, mk, 64);
                    int a = mt * 16 + hi * 4 + r;
                    if (lr == 0 && a < AN) Ls[w][a] = make_float2(m, e);
                }
            // transpose through LDS, then coalesced bf16 row stores
            __syncthreads();          // all waves done reading Bp
            #pragma unroll
            for (int mt = 0; mt < 3; ++mt)
                #pragma unroll
                for (int pt = 0; pt < 2; ++pt)
                    #pragma unroll
                    for (int r = 0; r < 4; ++r)
                        T[(mt * 16 + hi * 4 + r) * TST + (w * 2 + pt) * 16 + lr] =
                            f2bf(acc[mt][pt][r]);
            __syncthreads();
            unsigned short* dst = S1b + (size_t)b * AN * HW + n0;
            for (int u = t; u < AN * 16; u += 256) {
                int a = u >> 4, i = u & 15;
                if (n0 + i * 8 < HW)
                    *(s16x8*)&dst[(size_t)a * HW + i * 8] = *(s16x8*)&T[a * TST + i * 8];
            }
        } else {
            // per-pixel softmax over a, normalized in-register
            #pragma unroll
            for (int pt = 0; pt < 2; ++pt) {
                float pmax = -1e30f;
                #pragma unroll
                for (int mt = 0; mt < 3; ++mt)
                    #pragma unroll
                    for (int r = 0; r < 4; ++r) {
                        int a = mt * 16 + hi * 4 + r;
                        if (a < AN) pmax = fmaxf(pmax, acc[mt][pt][r]);
                    }
                pmax = fmaxf(pmax, __shfl_xor(pmax, 16, 64));
                pmax = fmaxf(pmax, __shfl_xor(pmax, 32, 64));
                float psum = 0.f;
                #pragma unroll
                for (int mt = 0; mt < 3; ++mt)
                    #pragma unroll
                    for (int r = 0; r < 4; ++r) {
                        int a = mt * 16 + hi * 4 + r;
                        float e = (a < AN) ? __expf(acc[mt][pt][r] - pmax) : 0.f;
                        acc[mt][pt][r] = e;
                        psum += e;
                    }
                psum += __shfl_xor(psum, 16, 64);
                psum += __shfl_xor(psum, 32, 64);
                float rs = 1.f / psum;
                #pragma unroll
                for (int mt = 0; mt < 3; ++mt)
                    #pragma unroll
                    for (int r = 0; r < 4; ++r)
                        acc[mt][pt][r] *= rs;
            }
            __syncthreads();          // all waves done reading Bp
            #pragma unroll
            for (int mt = 0; mt < 3; ++mt)
                #pragma unroll
                for (int pt = 0; pt < 2; ++pt)
                    #pragma unroll
                    for (int r = 0; r < 4; ++r)
                        T[(mt * 16 + hi * 4 + r) * TST + (w * 2 + pt) * 16 + lr] =
                            f2bf(acc[mt][pt][r]);
            __syncthreads();
            unsigned short* dst = S2n + (size_t)b * AN * HW + n0;
            for (int u = t; u < AN * 16; u += 256) {
                int a = u >> 4, i = u & 15;
                if (n0 + i * 8 < HW)
                    *(s16x8*)&dst[(size_t)a * HW + i * 8] = *(s16x8*)&T[a * TST + i * 8];
            }
        }
    }
    __syncthreads();
    if (t < AN) {
        float m = -1e30f, ssum = 0.f;
        #pragma unroll
        for (int wv = 0; wv < 4; ++wv) {
            float2 p = Ls[wv][t];
            float mn = fmaxf(m, p.x);
            ssum = ssum * __expf(m - mn) + p.y * __expf(p.x - mn);
            m = mn;
        }
        PS[((size_t)b * AN + t) * NBLK + bx] = make_float2(m, ssum);
    }
}

// ------- fused: row-stats from PS (redstats folded in), softmax(S1b),
//         pre-normalized S2n, conv1+BN2+ReLU, conv2(mean-folded) -------
__global__ __launch_bounds__(256) void k_fuse(const unsigned short* __restrict__ S1b,
                                              const float2* __restrict__ PS,
                                              const unsigned short* __restrict__ S2n,
                                              const float* __restrict__ w1,
                                              const float* __restrict__ g2,
                                              const float* __restrict__ b2,
                                              const float* __restrict__ m2,
                                              const float* __restrict__ v2,
                                              const float* __restrict__ w2,
                                              const float* __restrict__ bias2,
                                              unsigned short* __restrict__ AMb) {
    int b = blockIdx.y;
    int tid = threadIdx.x;
    int N = blockIdx.x * 256 + tid;
    __shared__ float W1f[MID * 72];
    __shared__ float b1f[MID];
    __shared__ float W2m[AN * MID];
    __shared__ float b2m[AN];
    __shared__ float sm_m[AN], sm_ri[AN];
    // row stats inline from PS (0.5 MB, L2-hot): threads 0..35 online-reduce a row
    if (tid < AN) {
        const float2* pr = PS + ((size_t)b * AN + tid) * NBLK;
        float m = -1e30f, s = 0.f;
        for (int i = 0; i < NBLK; ++i) {
            float2 p = pr[i];
            float mn = fmaxf(m, p.x);
            s = s * __expf(m - mn) + p.y * __expf(p.x - mn);
            m = mn;
        }
        sm_m[tid] = m;
        sm_ri[tid] = 1.f / s;
        float sb = 0.f;
        #pragma unroll
        for (int k = 0; k < 9; ++k) sb += bias2[tid * 9 + k];
        b2m[tid] = sb * (1.f / 9.f);
    }
    for (int i = tid; i < MID * 72; i += 256) {
        int m = i / 72;
        W1f[i] = w1[i] * (g2[m] * rsqrtf(v2[m] + EPS));
    }
    if (tid < MID) {
        float inv = g2[tid] * rsqrtf(v2[tid] + EPS);
        b1f[tid] = b2[tid] - m2[tid] * inv;
    }
    for (int i = tid; i < AN * MID; i += 256) {
        int a = i / MID, m = i % MID;
        float s = 0.f;
        #pragma unroll
        for (int k = 0; k < 9; ++k) s += w2[(a * 9 + k) * MID + m];
        W2m[i] = s * (1.f / 9.f);
    }
    __syncthreads();
    if (N >= HW) return;
    float yv[72];
    const unsigned short* a1p = S1b + (size_t)b * AN * HW + N;
    #pragma unroll
    for (int j = 0; j < AN; ++j)
        yv[j] = __expf(bf2f(a1p[(size_t)j * HW]) - sm_m[j]) * sm_ri[j];
    const unsigned short* s2p = S2n + (size_t)b * AN * HW + N;
    #pragma unroll
    for (int j = 0; j < AN; ++j) yv[AN + j] = bf2f(s2p[(size_t)j * HW]);
    float t[MID];
    #pragma unroll
    for (int m = 0; m < MID; ++m) {
        float a = b1f[m];
        #pragma unroll
        for (int j = 0; j < 72; ++j) a += W1f[m * 72 + j] * yv[j];
        t[m] = a > 0.f ? a : 0.f;
    }
    unsigned short* amp = AMb + (size_t)b * AN * HW + N;
    #pragma unroll
    for (int a = 0; a < AN; ++a) {
        float acc = b2m[a];
        #pragma unroll
        for (int m = 0; m < MID; ++m) acc += W2m[a * MID + m] * t[m];
        amp[(size_t)a * HW] = (unsigned short)f2bf(acc);
    }
}

// ------- out via MFMA: out[cc][n] = sum_a softmax36(AMb window)[a]*Vb[cc][a] + k1 -------
__global__ __launch_bounds__(256) void k_out_mfma(const unsigned short* __restrict__ AMb,
                                                  const unsigned short* __restrict__ Vb,
                                                  const unsigned short* __restrict__ k1b,
                                                  float* __restrict__ outp) {
    int b = blockIdx.y;
    int N0 = blockIdx.x * OPX;
    int t = threadIdx.x;
    __shared__ float smemf[4 * 1088];
    short* wl = (short*)smemf;

    {
        int p = t >> 2, q = t & 3;
        int N = N0 + p;
        int a = N / 400;
        int n0w = (N - a * 400) * AN;
        const unsigned short* amp = AMb + ((size_t)b * AN + a) * HW + n0w;
        const int qoff = (q == 0) ? 0 : (q == 1) ? 12 : (q == 2) ? 20 : 32;
        const int qn4 = (q == 0) ? 3 : (q == 1) ? 2 : (q == 2) ? 3 : 1;
        float vals[12];
        const u16x4* ap = (const u16x4*)(amp + qoff);
        #pragma unroll
        for (int i = 0; i < 3; ++i) {
            if (i < qn4) {
                u16x4 v = ap[i];
                vals[i * 4 + 0] = bf2f(v[0]); vals[i * 4 + 1] = bf2f(v[1]);
                vals[i * 4 + 2] = bf2f(v[2]); vals[i * 4 + 3] = bf2f(v[3]);
            }
        }
        int cnt = qn4 * 4;
        float m = -1e30f;
        #pragma unroll
        for (int i = 0; i < 12; ++i) if (i < cnt) m = fmaxf(m, vals[i]);
        m = fmaxf(m, __shfl_xor(m, 1, 64));
        m = fmaxf(m, __shfl_xor(m, 2, 64));
        float s = 0.f;
        #pragma unroll
        for (int i = 0; i < 12; ++i)
            if (i < cnt) { vals[i] = __expf(vals[i] - m); s += vals[i]; }
        s += __shfl_xor(s, 1, 64);
        s += __shfl_xor(s, 2, 64);
        float rs = 1.f / s;
        #pragma unroll
        for (int i = 0; i < 12; ++i)
            if (i < cnt) wl[p * WST + qoff + i] = f2bf(vals[i] * rs);
        if (q == 3) {
            #pragma unroll
            for (int i = 36; i < 64; ++i) wl[p * WST + i] = 0;
        }
    }
    __syncthreads();

    int w = t >> 6, l = t & 63, lr = l & 15, hi = l >> 4;
    int cc0 = w * 48;
    const s16x8* vb = (const s16x8*)(Vb + (size_t)b * C * 64);
    s16x8 Af[3][2];
    #pragma unroll
    for (int mt = 0; mt < 3; ++mt)
        #pragma unroll
        for (int ch = 0; ch < 2; ++ch)
            Af[mt][ch] = vb[(cc0 + mt * 16 + lr) * 8 + ch * 4 + hi];
    f32x4 acc[3][4];
    #pragma unroll
    for (int mt = 0; mt < 3; ++mt)
        #pragma unroll
        for (int pt = 0; pt < 4; ++pt)
            acc[mt][pt] = (f32x4){0.f, 0.f, 0.f, 0.f};
    #pragma unroll
    for (int pt = 0; pt < 4; ++pt) {
        s16x8 Bf[2];
        #pragma unroll
        for (int ch = 0; ch < 2; ++ch)
            Bf[ch] = *(const s16x8*)&wl[(pt * 16 + lr) * WST + ch * 32 + hi * 8];
        #pragma unroll
        for (int ch = 0; ch < 2; ++ch)
            #pragma unroll
            for (int mt = 0; mt < 3; ++mt)
                acc[mt][pt] = __builtin_amdgcn_mfma_f32_16x16x32_bf16(
                    Af[mt][ch], Bf[ch], acc[mt][pt], 0, 0, 0);
    }
    __syncthreads();

    float* T = smemf + (size_t)w * 1088;
    int px4 = (l & 15) * 4;
    #pragma unroll
    for (int mt = 0; mt < 3; ++mt) {
        u16x4 kk[4];
        float4 rf[4];
        #pragma unroll
        for (int pass = 0; pass < 4; ++pass) {
            int ccr = pass * 4 + hi;
            int cc = cc0 + mt * 16 + ccr;
            size_t idx = ((size_t)(b * C + cc)) * HW + N0 + px4;
            if (k1b) kk[pass] = *(const u16x4*)&k1b[idx];
            else rf[pass] = *(float4*)&outp[idx];
        }
        #pragma unroll
        for (int pt = 0; pt < 4; ++pt)
            #pragma unroll
            for (int r = 0; r < 4; ++r)
                T[(hi * 4 + r) * 68 + pt * 16 + lr] = acc[mt][pt][r];
        #pragma unroll
        for (int pass = 0; pass < 4; ++pass) {
            int ccr = pass * 4 + hi;
            float4 vv = *(float4*)&T[ccr * 68 + px4];
            int cc = cc0 + mt * 16 + ccr;
            size_t idx = ((size_t)(b * C + cc)) * HW + N0 + px4;
            float4 res;
            if (k1b) res = make_float4(bf2f(kk[pass][0]), bf2f(kk[pass][1]),
                                       bf2f(kk[pass][2]), bf2f(kk[pass][3]));
            else res = rf[pass];
            vv.x += res.x; vv.y += res.y; vv.z += res.z; vv.w += res.w;
            *(float4*)&outp[idx] = vv;
        }
    }
}

extern "C" void kernel_launch(void* const* d_in, const int* in_sizes, int n_in,
                              void* d_out, int out_size, void* d_ws, size_t ws_size,
                              hipStream_t stream) {
    const float* x      = (const float*)d_in[0];
    const float* key_w  = (const float*)d_in[1];
    const float* bn1_g  = (const float*)d_in[2];
    const float* bn1_b  = (const float*)d_in[3];
    const float* bn1_m  = (const float*)d_in[4];
    const float* bn1_v  = (const float*)d_in[5];
    const float* val_w  = (const float*)d_in[6];
    const float* att_w1 = (const float*)d_in[7];
    const float* bn2_g  = (const float*)d_in[8];
    const float* bn2_b  = (const float*)d_in[9];
    const float* bn2_m  = (const float*)d_in[10];
    const float* bn2_v  = (const float*)d_in[11];
    const float* att_w2 = (const float*)d_in[12];
    const float* att_b2 = (const float*)d_in[13];
    float* out = (float*)d_out;

    unsigned char* base = (unsigned char*)d_ws;
    size_t off = 0;
    unsigned short* Wq = (unsigned short*)(base + off); off += 221184;
    unsigned short* Vb = (unsigned short*)(base + off); off += 393216;
    float* P  = (float*)(base + off); off += 442368;
    float* ST = (float*)(base + off); off += 4608;   // (unused; layout kept)
    float2* PS = (float2*)(base + off); off += 520704;    // 576*113*8
    unsigned char* big = base + off;
    size_t nS2 = (size_t)BS * AN * HW * 2;                // 16,588,800
    size_t xtpBytes = (size_t)BS * 24 * XROWS * XCOLS * 16;  // 98,942,976
    unsigned short* S1b = (unsigned short*)big;
    unsigned short* S2n = (unsigned short*)(big + nS2);
    unsigned short* AMb = (unsigned short*)(big + 2 * nS2);
    off += xtpBytes;                                      // big region reservation
    size_t k1bBytes = (size_t)BS * C * HW * 2;            // 88,473,600
    unsigned short* k1b = nullptr;
    unsigned short* xTp = (unsigned short*)big;           // fallback alias
    int xtpSep = 0;
    if (ws_size >= off + k1bBytes) {
        k1b = (unsigned short*)(base + off); off += k1bBytes;
        if (ws_size >= off + xtpBytes) {
            xTp = (unsigned short*)(base + off); off += xtpBytes;
            xtpSep = 1;
        }
    }
    int writeF32 = (k1b == nullptr) ? 1 : 0;
    (void)ST;

    k_wfold<<<(NWQ + 255) / 256, 256, 0, stream>>>(key_w, bn1_g, bn1_v, Wq);
    k_xt<<<dim3(H, BS), 256, 0, stream>>>(x, xTp);
    k_pool_b<<<dim3(24, BS), 256, 0, stream>>>(xTp, P);
    k_val<<<BS, 256, 0, stream>>>(val_w, P, Vb);
    k_conv_mfma<<<dim3(H / 2, 3, BS), 256, 0, stream>>>(
        xTp, Wq, bn1_g, bn1_b, bn1_m, bn1_v, out, k1b, writeF32);
    k_scores_mfma<<<dim3(NBLK, BS), 256, 0, stream>>>(
        P, out, k1b, x, xtpSep ? xTp : nullptr, S1b, S2n, PS);
    k_fuse<<<dim3((HW + 255) / 256, BS), 256, 0, stream>>>(
        S1b, PS, S2n, att_w1, bn2_g, bn2_b, bn2_m, bn2_v, att_w2, att_b2, AMb);
    k_out_mfma<<<dim3(HW / OPX, BS), 256, 0, stream>>>(AMb, Vb, k1b, out);
}

// Round 14
// 447.743 us; speedup vs baseline: 1.0467x; 1.0356x over previous
//
#include <hip/hip_runtime.h>
#include <hip/hip_bf16.h>
#include <math.h>

#define BS 16
#define C 192
#define H 120
#define W 120
#define HW 14400
#define AN 36
#define MID 18
#define CPG 64
#define EPS 1e-5f
#define SPX 128
#define BPS 200
#define NWQ 13824   // 3g * 2cc * 9tap * 4hi * 64co units (16B each)
#define XROWS 122
#define XCOLS 132
#define OPX 64      // k_out pixels per block
#define WST 72      // k_out w LDS stride (shorts)
#define NBLK 113    // score blocks per batch
#define TST 132     // transpose-tile stride (shorts)

typedef __attribute__((ext_vector_type(8))) short s16x8;
typedef __attribute__((ext_vector_type(4))) float f32x4;
typedef __attribute__((ext_vector_type(4))) unsigned short u16x4;

static __device__ __forceinline__ short f2bf(float f) {
    union { float f; unsigned u; } v; v.f = f;
    unsigned r = (v.u + 0x7FFF + ((v.u >> 16) & 1)) >> 16;
    return (short)r;
}
static __device__ __forceinline__ float bf2f(unsigned short u) {
    union { unsigned u; float f; } v; v.u = ((unsigned)u) << 16;
    return v.f;
}
static __device__ __forceinline__ s16x8 cvt8(float4 f0, float4 f1) {
    s16x8 v;
    v[0] = f2bf(f0.x); v[1] = f2bf(f0.y); v[2] = f2bf(f0.z); v[3] = f2bf(f0.w);
    v[4] = f2bf(f1.x); v[5] = f2bf(f1.y); v[6] = f2bf(f1.z); v[7] = f2bf(f1.w);
    return v;
}

// ------- fold BN1 into key_w, bf16, B-fragment layout -------
__global__ __launch_bounds__(256) void k_wfold(const float* __restrict__ kw,
                                               const float* __restrict__ g1,
                                               const float* __restrict__ v1,
                                               unsigned short* __restrict__ Wq) {
    int u = blockIdx.x * 256 + threadIdx.x;
    if (u >= NWQ) return;
    int gc = u / 2304, rem = u - gc * 2304;
    int g = gc >> 1, cc = gc & 1;
    int th = rem >> 6, co = rem & 63;
    int tap = th >> 2, hi = th & 3;
    int cog = g * 64 + co;
    float inv = g1[cog] * rsqrtf(v1[cog] + EPS);
    const float* wp = kw + ((size_t)cog * 64 + cc * 32 + hi * 8) * 9 + tap;
    s16x8 v;
    #pragma unroll
    for (int e = 0; e < 8; ++e) v[e] = f2bf(wp[e * 9] * inv);
    *(s16x8*)&Wq[(size_t)u * 8] = v;
}

// ------- xTp: x f32 [b,c,hw] -> bf16 [b][oct24][row 122][col 132][8], zero halo -------
__global__ __launch_bounds__(256) void k_xt(const float* __restrict__ x,
                                            unsigned short* __restrict__ xTp) {
    int y = blockIdx.x, b = blockIdx.y;
    int t = threadIdx.x;
    __shared__ unsigned short L[120 * 200];
    for (int u = t; u < 24 * 120; u += 256) {
        int oc = u / 120, px = u - oc * 120;
        const float* xp = x + ((size_t)b * C + oc * 8) * HW + y * W + px;
        s16x8 v;
        #pragma unroll
        for (int j = 0; j < 8; ++j) v[j] = f2bf(xp[(size_t)j * HW]);
        *(s16x8*)&L[px * 200 + oc * 8] = v;
    }
    __syncthreads();
    for (int u = t; u < 24 * XCOLS; u += 256) {
        int oc = u / XCOLS, p = u - oc * XCOLS;
        int px = p - 1;
        s16x8 v = {0, 0, 0, 0, 0, 0, 0, 0};
        if (px >= 0 && px < 120) v = *(const s16x8*)&L[px * 200 + oc * 8];
        *(s16x8*)&xTp[(((size_t)(b * 24 + oc)) * XROWS + (y + 1)) * XCOLS * 8 + p * 8] = v;
    }
    if (y == 0 || y == H - 1) {
        int r = (y == 0) ? 0 : XROWS - 1;
        s16x8 z = {0, 0, 0, 0, 0, 0, 0, 0};
        for (int u = t; u < 24 * XCOLS; u += 256) {
            int oc = u / XCOLS, p = u - oc * XCOLS;
            *(s16x8*)&xTp[(((size_t)(b * 24 + oc)) * XROWS + r) * XCOLS * 8 + p * 8] = z;
        }
    }
}

// ------- pool6 from bf16 xTp (L3-hot): P[b][c][36] f32 -------
__global__ __launch_bounds__(256) void k_pool_b(const unsigned short* __restrict__ xTp,
                                                float* __restrict__ P) {
    int oc = blockIdx.x, b = blockIdx.y;
    int t = threadIdx.x;
    __shared__ float Lp[240 * 24];
    const unsigned short* base =
        xTp + (((size_t)(b * 24 + oc)) * XROWS + 1) * XCOLS * 8 + 8;
    if (t < 240) {
        int y = t >> 1, h = t & 1;
        const unsigned short* row = base + (size_t)y * XCOLS * 8 + h * 60 * 8;
        float acc[3][8];
        #pragma unroll
        for (int qq = 0; qq < 3; ++qq)
            #pragma unroll
            for (int e = 0; e < 8; ++e) acc[qq][e] = 0.f;
        #pragma unroll
        for (int qq = 0; qq < 3; ++qq)
            for (int j = 0; j < 20; ++j) {
                s16x8 v = *(const s16x8*)&row[(qq * 20 + j) * 8];
                #pragma unroll
                for (int e = 0; e < 8; ++e) acc[qq][e] += bf2f((unsigned short)v[e]);
            }
        #pragma unroll
        for (int qq = 0; qq < 3; ++qq)
            #pragma unroll
            for (int e = 0; e < 8; ++e) Lp[t * 24 + qq * 8 + e] = acc[qq][e];
    }
    __syncthreads();
    if (t < 288) {
        int seg = t >> 3, e = t & 7;
        int yq = seg / 6, q = seg % 6;
        int h = q / 3, qq = q % 3;
        float s = 0.f;
        for (int j = 0; j < 20; ++j)
            s += Lp[((yq * 20 + j) * 2 + h) * 24 + qq * 8 + e];
        P[((size_t)b * C + oc * 8 + e) * AN + seg] = s * (1.f / 400.f);
    }
}

// ------- Vb[b][cc][64] bf16 = val_w @ pooled (a>=36 zero-padded) -------
__global__ __launch_bounds__(256) void k_val(const float* __restrict__ valw,
                                             const float* __restrict__ P,
                                             unsigned short* __restrict__ Vb) {
    int b = blockIdx.x;
    __shared__ float Pl[C * AN];
    int tid = threadIdx.x;
    for (int i = tid; i < C * AN; i += 256) Pl[i] = P[(size_t)b * C * AN + i];
    __syncthreads();
    for (int o = tid; o < C * 8; o += 256) {
        int cc = o >> 3, a8 = o & 7;
        s16x8 vv = {0, 0, 0, 0, 0, 0, 0, 0};
        #pragma unroll
        for (int j = 0; j < 8; ++j) {
            int a = a8 * 8 + j;
            if (a < AN) {
                float s = 0.f;
                for (int k = 0; k < C; ++k) s += valw[cc * C + k] * Pl[k * AN + a];
                vv[j] = f2bf(s);
            }
        }
        *(s16x8*)&Vb[((size_t)b * C + cc) * 64 + a8 * 8] = vv;
    }
}

// ------------- grouped 3x3 conv + BN1 + ReLU, implicit-GEMM MFMA -------------
__global__ __launch_bounds__(256, 4) void k_conv_mfma(
        const unsigned short* __restrict__ xTp, const unsigned short* __restrict__ Wq,
        const float* __restrict__ g1, const float* __restrict__ b1,
        const float* __restrict__ m1, const float* __restrict__ v1,
        float* __restrict__ k1f, unsigned short* __restrict__ k1b, int writeF32) {
    int yp = blockIdx.x, g = blockIdx.y, b = blockIdx.z;
    int y0 = yp * 2;
    int t = threadIdx.x;
    __shared__ short xl[(2048 + 2) * 8];

    int w = t >> 6, l = t & 63, lr = l & 15, hi = l >> 4;
    int ry = w >> 1, xh = w & 1;
    f32x4 acc[4][4];
    #pragma unroll
    for (int mt = 0; mt < 4; ++mt)
        #pragma unroll
        for (int nt = 0; nt < 4; ++nt)
            acc[mt][nt] = (f32x4){0.f, 0.f, 0.f, 0.f};

    for (int cc = 0; cc < 2; ++cc) {
        if (cc) __syncthreads();
        const unsigned short* xbase =
            xTp + ((size_t)((b * 24 + g * 8 + cc * 4) * XROWS) + y0) * XCOLS * 8;
        #pragma unroll
        for (int k = 0; k < 8; ++k) {
            int u = t + 256 * k;
            int run = u >> 7, p = u & 127;
            int oct = run >> 2, r = run & 3;
            s16x8 v = *(const s16x8*)&xbase[((size_t)(oct * XROWS + r)) * XCOLS * 8 + p * 8];
            *(s16x8*)&xl[u * 8] = v;
        }
        __syncthreads();
        const s16x8* wq = (const s16x8*)Wq + (size_t)(g * 2 + cc) * 2304;
        s16x8 Bn[4];
        #pragma unroll
        for (int nt = 0; nt < 4; ++nt) Bn[nt] = wq[hi * 64 + nt * 16 + lr];
        #pragma unroll
        for (int tap = 0; tap < 9; ++tap) {
            int ky = tap / 3, kx = tap % 3;
            s16x8 Bc[4];
            #pragma unroll
            for (int nt = 0; nt < 4; ++nt) Bc[nt] = Bn[nt];
            if (tap < 8) {
                #pragma unroll
                for (int nt = 0; nt < 4; ++nt)
                    Bn[nt] = wq[((tap + 1) * 4 + hi) * 64 + nt * 16 + lr];
            }
            s16x8 A[4];
            #pragma unroll
            for (int mt = 0; mt < 4; ++mt) {
                int col = xh * 64 + mt * 16 + lr + kx;
                A[mt] = *(const s16x8*)&xl[((hi * 4 + ry + ky) * 128 + col) * 8];
            }
            #pragma unroll
            for (int mt = 0; mt < 4; ++mt)
                #pragma unroll
                for (int nt = 0; nt < 4; ++nt)
                    acc[mt][nt] = __builtin_amdgcn_mfma_f32_16x16x32_bf16(
                        A[mt], Bc[nt], acc[mt][nt], 0, 0, 0);
        }
    }
    int y = y0 + ry;
    #pragma unroll
    for (int nt = 0; nt < 4; ++nt) {
        int cog = g * CPG + nt * 16 + lr;
        float inv = g1[cog] * rsqrtf(v1[cog] + EPS);
        float beta = b1[cog] - m1[cog] * inv;
        #pragma unroll
        for (int mt = 0; mt < 4; ++mt) {
            int xcol = xh * 64 + mt * 16 + hi * 4;
            if (xcol >= 120) continue;
            float r0 = fmaxf(acc[mt][nt][0] + beta, 0.f);
            float r1 = fmaxf(acc[mt][nt][1] + beta, 0.f);
            float r2 = fmaxf(acc[mt][nt][2] + beta, 0.f);
            float r3 = fmaxf(acc[mt][nt][3] + beta, 0.f);
            size_t base = ((size_t)(b * C + cog)) * HW + y * W + xcol;
            if (writeF32) {
                *(float4*)&k1f[base] = make_float4(r0, r1, r2, r3);
            } else {
                u16x4 q;
                q[0] = (unsigned short)f2bf(r0); q[1] = (unsigned short)f2bf(r1);
                q[2] = (unsigned short)f2bf(r2); q[3] = (unsigned short)f2bf(r3);
                *(u16x4*)&k1b[base] = q;
            }
        }
    }
}

// ------- scores via MFMA: S1b = bf16 logits + block softmax partials;
//         S2n = per-pixel-normalized bf16 q_attn. Coalesced stores via LDS transpose. -------
__global__ __launch_bounds__(256, 3) void k_scores_mfma(
        const float* __restrict__ Pp, const float* __restrict__ k1f,
        const unsigned short* __restrict__ k1b, const float* __restrict__ x,
        const unsigned short* __restrict__ xTp,
        unsigned short* __restrict__ S1b, unsigned short* __restrict__ S2n,
        float2* __restrict__ PS) {
    int b = blockIdx.y;
    int bx = blockIdx.x;
    int n0 = bx * SPX;
    int t = threadIdx.x;
    int w = t >> 6, l = t & 63, lr = l & 15, hi = l >> 4;
    __shared__ short Bp[SPX * BPS];
    __shared__ float2 Ls[4][40];
    short* T = Bp;   // transpose tile alias: [48][TST]

    s16x8 afr[3][6];
    const float* ab = Pp + (size_t)b * (C * AN);
    #pragma unroll
    for (int mt = 0; mt < 3; ++mt) {
        int row = mt * 16 + lr;
        #pragma unroll
        for (int kc = 0; kc < 6; ++kc) {
            s16x8 v = {0, 0, 0, 0, 0, 0, 0, 0};
            if (row < AN) {
                const float4* ap = (const float4*)(ab + row * C + kc * 32 + hi * 8);
                v = cvt8(ap[0], ap[1]);
            }
            afr[mt][kc] = v;
        }
    }

    #pragma unroll 1
    for (int s = 0; s < 2; ++s) {
        __syncthreads();
        if (s == 0 && k1b) {
            const unsigned short* src = k1b + (size_t)b * C * HW + (size_t)n0 * C;
            for (int i = t; i < SPX * 24; i += 256) {
                int row = i / 24, o = i - row * 24;
                s16x8 v = {0, 0, 0, 0, 0, 0, 0, 0};
                if (n0 + row < HW) v = *(const s16x8*)&src[row * C + o * 8];
                *(s16x8*)&Bp[row * BPS + o * 8] = v;
            }
        } else if (s == 1 && xTp) {
            for (int i = t; i < SPX * 24; i += 256) {
                int row = i / 24, oc = i - row * 24;
                int n = n0 + row;
                s16x8 v = {0, 0, 0, 0, 0, 0, 0, 0};
                if (n < HW) {
                    int yy = n / 120, xx = n - yy * 120;
                    v = *(const s16x8*)&xTp[(((size_t)(b * 24 + oc)) * XROWS + yy + 1) *
                                            XCOLS * 8 + (xx + 1) * 8];
                }
                *(s16x8*)&Bp[row * BPS + oc * 8] = v;
            }
        } else {
            const float* sf = (s == 0) ? k1f : x;
            const float4* src = (const float4*)(sf + (size_t)b * C * HW + (size_t)n0 * C);
            for (int i = t; i < SPX * 24; i += 256) {
                int row = i / 24, c8 = (i - row * 24) * 8;
                s16x8 v = {0, 0, 0, 0, 0, 0, 0, 0};
                if (n0 + row < HW)
                    v = cvt8(src[row * 48 + c8 / 4], src[row * 48 + c8 / 4 + 1]);
                *(s16x8*)&Bp[row * BPS + c8] = v;
            }
        }
        __syncthreads();
        f32x4 acc[3][2];
        #pragma unroll
        for (int mt = 0; mt < 3; ++mt)
            #pragma unroll
            for (int pt = 0; pt < 2; ++pt)
                acc[mt][pt] = (f32x4){0.f, 0.f, 0.f, 0.f};
        #pragma unroll
        for (int kc = 0; kc < 6; ++kc) {
            s16x8 bf[2];
            #pragma unroll
            for (int pt = 0; pt < 2; ++pt) {
                int px = (w * 2 + pt) * 16 + lr;
                bf[pt] = *(const s16x8*)&Bp[px * BPS + kc * 32 + hi * 8];
            }
            #pragma unroll
            for (int mt = 0; mt < 3; ++mt)
                #pragma unroll
                for (int pt = 0; pt < 2; ++pt)
                    acc[mt][pt] = __builtin_amdgcn_mfma_f32_16x16x32_bf16(
                        afr[mt][kc], bf[pt], acc[mt][pt], 0, 0, 0);
        }
        if (s == 0) {
            // per-block online-softmax partials per a-row (register/shuffle only)
            bool ok0 = (n0 + (w * 2) * 16 + lr) < HW;
            bool ok1 = (n0 + (w * 2 + 1) * 16 + lr) < HW;
            #pragma unroll
            for (int mt = 0; mt < 3; ++mt)
                #pragma unroll
                for (int r = 0; r < 4; ++r) {
                    float v0 = ok0 ? acc[mt][0][r] : -1e30f;
                    float v1 = ok1 ? acc[mt][1][r] : -1e30f;
                    float m = fmaxf(v0, v1);
                    #pragma unroll
                    for (int mk = 1; mk <= 8; mk <<= 1)
                        m = fmaxf(m, __shfl_xor(m, mk, 64));
                    float e = (ok0 ? __expf(v0 - m) : 0.f) + (ok1 ? __expf(v1 - m) : 0.f);
                    #pragma unroll
                    for (int mk = 1; mk <= 8; mk <<= 1)
                        e += __shfl_xor(e, mk, 64);
                    int a = mt * 16 + hi * 4 + r;
                    if (lr == 0 && a < AN) Ls[w][a] = make_float2(m, e);
                }
            // transpose through LDS, then coalesced bf16 row stores
            __syncthreads();          // all waves done reading Bp
            #pragma unroll
            for (int mt = 0; mt < 3; ++mt)
                #pragma unroll
                for (int pt = 0; pt < 2; ++pt)
                    #pragma unroll
                    for (int r = 0; r < 4; ++r)
                        T[(mt * 16 + hi * 4 + r) * TST + (w * 2 + pt) * 16 + lr] =
                            f2bf(acc[mt][pt][r]);
            __syncthreads();
            unsigned short* dst = S1b + (size_t)b * AN * HW + n0;
            for (int u = t; u < AN * 16; u += 256) {
                int a = u >> 4, i = u & 15;
                if (n0 + i * 8 < HW)
                    *(s16x8*)&dst[(size_t)a * HW + i * 8] = *(s16x8*)&T[a * TST + i * 8];
            }
        } else {
            // per-pixel softmax over a, normalized in-register
            #pragma unroll
            for (int pt = 0; pt < 2; ++pt) {
                float pmax = -1e30f;
                #pragma unroll
                for (int mt = 0; mt < 3; ++mt)
                    #pragma unroll
                    for (int r = 0; r < 4; ++r) {
                        int a = mt * 16 + hi * 4 + r;
                        if (a < AN) pmax = fmaxf(pmax, acc[mt][pt][r]);
                    }
                pmax = fmaxf(pmax, __shfl_xor(pmax, 16, 64));
                pmax = fmaxf(pmax, __shfl_xor(pmax, 32, 64));
                float psum = 0.f;
                #pragma unroll
                for (int mt = 0; mt < 3; ++mt)
                    #pragma unroll
                    for (int r = 0; r < 4; ++r) {
                        int a = mt * 16 + hi * 4 + r;
                        float e = (a < AN) ? __expf(acc[mt][pt][r] - pmax) : 0.f;
                        acc[mt][pt][r] = e;
                        psum += e;
                    }
                psum += __shfl_xor(psum, 16, 64);
                psum += __shfl_xor(psum, 32, 64);
                float rs = 1.f / psum;
                #pragma unroll
                for (int mt = 0; mt < 3; ++mt)
                    #pragma unroll
                    for (int r = 0; r < 4; ++r)
                        acc[mt][pt][r] *= rs;
            }
            __syncthreads();          // all waves done reading Bp
            #pragma unroll
            for (int mt = 0; mt < 3; ++mt)
                #pragma unroll
                for (int pt = 0; pt < 2; ++pt)
                    #pragma unroll
                    for (int r = 0; r < 4; ++r)
                        T[(mt * 16 + hi * 4 + r) * TST + (w * 2 + pt) * 16 + lr] =
                            f2bf(acc[mt][pt][r]);
            __syncthreads();
            unsigned short* dst = S2n + (size_t)b * AN * HW + n0;
            for (int u = t; u < AN * 16; u += 256) {
                int a = u >> 4, i = u & 15;
                if (n0 + i * 8 < HW)
                    *(s16x8*)&dst[(size_t)a * HW + i * 8] = *(s16x8*)&T[a * TST + i * 8];
            }
        }
    }
    __syncthreads();
    if (t < AN) {
        float m = -1e30f, ssum = 0.f;
        #pragma unroll
        for (int wv = 0; wv < 4; ++wv) {
            float2 p = Ls[wv][t];
            float mn = fmaxf(m, p.x);
            ssum = ssum * __expf(m - mn) + p.y * __expf(p.x - mn);
            m = mn;
        }
        PS[((size_t)b * AN + t) * NBLK + bx] = make_float2(m, ssum);
    }
}

// ------- reduce per-block partials -> row stats (max, 1/sum) -------
__global__ __launch_bounds__(128) void k_redstats(const float2* __restrict__ PS,
                                                  float* __restrict__ stats) {
    int row = blockIdx.x;
    int t = threadIdx.x;
    float m = -1e30f, s = 0.f;
    for (int i = t; i < NBLK; i += 128) {
        float2 p = PS[(size_t)row * NBLK + i];
        float mn = fmaxf(m, p.x);
        s = s * __expf(m - mn) + p.y * __expf(p.x - mn);
        m = mn;
    }
    #pragma unroll
    for (int off = 32; off > 0; off >>= 1) {
        float om = __shfl_down(m, off, 64);
        float os = __shfl_down(s, off, 64);
        float mn = fmaxf(m, om);
        s = s * __expf(m - mn) + os * __expf(om - mn);
        m = mn;
    }
    __shared__ float2 red[2];
    if ((t & 63) == 0) red[t >> 6] = make_float2(m, s);
    __syncthreads();
    if (t == 0) {
        float2 a = red[0], bb = red[1];
        float mn = fmaxf(a.x, bb.x);
        float ss = a.y * __expf(a.x - mn) + bb.y * __expf(bb.x - mn);
        stats[row] = mn;
        stats[576 + row] = 1.f / ss;
    }
}

// ------- fused: softmax(S1b) via stats, pre-normalized S2n, conv1+BN2+ReLU, conv2 -------
__global__ __launch_bounds__(256) void k_fuse(const unsigned short* __restrict__ S1b,
                                              const float* __restrict__ stats,
                                              const unsigned short* __restrict__ S2n,
                                              const float* __restrict__ w1,
                                              const float* __restrict__ g2,
                                              const float* __restrict__ b2,
                                              const float* __restrict__ m2,
                                              const float* __restrict__ v2,
                                              const float* __restrict__ w2,
                                              const float* __restrict__ bias2,
                                              unsigned short* __restrict__ AMb) {
    int b = blockIdx.y;
    int tid = threadIdx.x;
    int N = blockIdx.x * 256 + tid;
    __shared__ float W1f[MID * 72];
    __shared__ float b1f[MID];
    __shared__ float W2m[AN * MID];
    __shared__ float b2m[AN];
    __shared__ float sm_m[AN], sm_ri[AN];
    for (int i = tid; i < MID * 72; i += 256) {
        int m = i / 72;
        W1f[i] = w1[i] * (g2[m] * rsqrtf(v2[m] + EPS));
    }
    if (tid < MID) {
        float inv = g2[tid] * rsqrtf(v2[tid] + EPS);
        b1f[tid] = b2[tid] - m2[tid] * inv;
    }
    for (int i = tid; i < AN * MID; i += 256) {
        int a = i / MID, m = i % MID;
        float s = 0.f;
        #pragma unroll
        for (int k = 0; k < 9; ++k) s += w2[(a * 9 + k) * MID + m];
        W2m[i] = s * (1.f / 9.f);
    }
    if (tid < AN) {
        float s = 0.f;
        #pragma unroll
        for (int k = 0; k < 9; ++k) s += bias2[tid * 9 + k];
        b2m[tid] = s * (1.f / 9.f);
        sm_m[tid] = stats[b * AN + tid];
        sm_ri[tid] = stats[576 + b * AN + tid];
    }
    __syncthreads();
    if (N >= HW) return;
    float yv[72];
    const unsigned short* a1p = S1b + (size_t)b * AN * HW + N;
    #pragma unroll
    for (int j = 0; j < AN; ++j)
        yv[j] = __expf(bf2f(a1p[(size_t)j * HW]) - sm_m[j]) * sm_ri[j];
    const unsigned short* s2p = S2n + (size_t)b * AN * HW + N;
    #pragma unroll
    for (int j = 0; j < AN; ++j) yv[AN + j] = bf2f(s2p[(size_t)j * HW]);
    float t[MID];
    #pragma unroll
    for (int m = 0; m < MID; ++m) {
        float a = b1f[m];
        #pragma unroll
        for (int j = 0; j < 72; ++j) a += W1f[m * 72 + j] * yv[j];
        t[m] = a > 0.f ? a : 0.f;
    }
    unsigned short* amp = AMb + (size_t)b * AN * HW + N;
    #pragma unroll
    for (int a = 0; a < AN; ++a) {
        float acc = b2m[a];
        #pragma unroll
        for (int m = 0; m < MID; ++m) acc += W2m[a * MID + m] * t[m];
        amp[(size_t)a * HW] = (unsigned short)f2bf(acc);
    }
}

// ------- out via MFMA: out[cc][n] = sum_a softmax36(AMb window)[a]*Vb[cc][a] + k1 -------
__global__ __launch_bounds__(256) void k_out_mfma(const unsigned short* __restrict__ AMb,
                                                  const unsigned short* __restrict__ Vb,
                                                  const unsigned short* __restrict__ k1b,
                                                  float* __restrict__ outp) {
    int b = blockIdx.y;
    int N0 = blockIdx.x * OPX;
    int t = threadIdx.x;
    __shared__ float smemf[4 * 1088];
    short* wl = (short*)smemf;

    {
        int p = t >> 2, q = t & 3;
        int N = N0 + p;
        int a = N / 400;
        int n0w = (N - a * 400) * AN;
        const unsigned short* amp = AMb + ((size_t)b * AN + a) * HW + n0w;
        const int qoff = (q == 0) ? 0 : (q == 1) ? 12 : (q == 2) ? 20 : 32;
        const int qn4 = (q == 0) ? 3 : (q == 1) ? 2 : (q == 2) ? 3 : 1;
        float vals[12];
        const u16x4* ap = (const u16x4*)(amp + qoff);
        #pragma unroll
        for (int i = 0; i < 3; ++i) {
            if (i < qn4) {
                u16x4 v = ap[i];
                vals[i * 4 + 0] = bf2f(v[0]); vals[i * 4 + 1] = bf2f(v[1]);
                vals[i * 4 + 2] = bf2f(v[2]); vals[i * 4 + 3] = bf2f(v[3]);
            }
        }
        int cnt = qn4 * 4;
        float m = -1e30f;
        #pragma unroll
        for (int i = 0; i < 12; ++i) if (i < cnt) m = fmaxf(m, vals[i]);
        m = fmaxf(m, __shfl_xor(m, 1, 64));
        m = fmaxf(m, __shfl_xor(m, 2, 64));
        float s = 0.f;
        #pragma unroll
        for (int i = 0; i < 12; ++i)
            if (i < cnt) { vals[i] = __expf(vals[i] - m); s += vals[i]; }
        s += __shfl_xor(s, 1, 64);
        s += __shfl_xor(s, 2, 64);
        float rs = 1.f / s;
        #pragma unroll
        for (int i = 0; i < 12; ++i)
            if (i < cnt) wl[p * WST + qoff + i] = f2bf(vals[i] * rs);
        if (q == 3) {
            #pragma unroll
            for (int i = 36; i < 64; ++i) wl[p * WST + i] = 0;
        }
    }
    __syncthreads();

    int w = t >> 6, l = t & 63, lr = l & 15, hi = l >> 4;
    int cc0 = w * 48;
    const s16x8* vb = (const s16x8*)(Vb + (size_t)b * C * 64);
    s16x8 Af[3][2];
    #pragma unroll
    for (int mt = 0; mt < 3; ++mt)
        #pragma unroll
        for (int ch = 0; ch < 2; ++ch)
            Af[mt][ch] = vb[(cc0 + mt * 16 + lr) * 8 + ch * 4 + hi];
    f32x4 acc[3][4];
    #pragma unroll
    for (int mt = 0; mt < 3; ++mt)
        #pragma unroll
        for (int pt = 0; pt < 4; ++pt)
            acc[mt][pt] = (f32x4){0.f, 0.f, 0.f, 0.f};
    #pragma unroll
    for (int pt = 0; pt < 4; ++pt) {
        s16x8 Bf[2];
        #pragma unroll
        for (int ch = 0; ch < 2; ++ch)
            Bf[ch] = *(const s16x8*)&wl[(pt * 16 + lr) * WST + ch * 32 + hi * 8];
        #pragma unroll
        for (int ch = 0; ch < 2; ++ch)
            #pragma unroll
            for (int mt = 0; mt < 3; ++mt)
                acc[mt][pt] = __builtin_amdgcn_mfma_f32_16x16x32_bf16(
                    Af[mt][ch], Bf[ch], acc[mt][pt], 0, 0, 0);
    }
    __syncthreads();

    float* T = smemf + (size_t)w * 1088;
    int px4 = (l & 15) * 4;
    #pragma unroll
    for (int mt = 0; mt < 3; ++mt) {
        u16x4 kk[4];
        float4 rf[4];
        #pragma unroll
        for (int pass = 0; pass < 4; ++pass) {
            int ccr = pass * 4 + hi;
            int cc = cc0 + mt * 16 + ccr;
            size_t idx = ((size_t)(b * C + cc)) * HW + N0 + px4;
            if (k1b) kk[pass] = *(const u16x4*)&k1b[idx];
            else rf[pass] = *(float4*)&outp[idx];
        }
        #pragma unroll
        for (int pt = 0; pt < 4; ++pt)
            #pragma unroll
            for (int r = 0; r < 4; ++r)
                T[(hi * 4 + r) * 68 + pt * 16 + lr] = acc[mt][pt][r];
        #pragma unroll
        for (int pass = 0; pass < 4; ++pass) {
            int ccr = pass * 4 + hi;
            float4 vv = *(float4*)&T[ccr * 68 + px4];
            int cc = cc0 + mt * 16 + ccr;
            size_t idx = ((size_t)(b * C + cc)) * HW + N0 + px4;
            float4 res;
            if (k1b) res = make_float4(bf2f(kk[pass][0]), bf2f(kk[pass][1]),
                                       bf2f(kk[pass][2]), bf2f(kk[pass][3]));
            else res = rf[pass];
            vv.x += res.x; vv.y += res.y; vv.z += res.z; vv.w += res.w;
            *(float4*)&outp[idx] = vv;
        }
    }
}

extern "C" void kernel_launch(void* const* d_in, const int* in_sizes, int n_in,
                              void* d_out, int out_size, void* d_ws, size_t ws_size,
                              hipStream_t stream) {
    const float* x      = (const float*)d_in[0];
    const float* key_w  = (const float*)d_in[1];
    const float* bn1_g  = (const float*)d_in[2];
    const float* bn1_b  = (const float*)d_in[3];
    const float* bn1_m  = (const float*)d_in[4];
    const float* bn1_v  = (const float*)d_in[5];
    const float* val_w  = (const float*)d_in[6];
    const float* att_w1 = (const float*)d_in[7];
    const float* bn2_g  = (const float*)d_in[8];
    const float* bn2_b  = (const float*)d_in[9];
    const float* bn2_m  = (const float*)d_in[10];
    const float* bn2_v  = (const float*)d_in[11];
    const float* att_w2 = (const float*)d_in[12];
    const float* att_b2 = (const float*)d_in[13];
    float* out = (float*)d_out;

    unsigned char* base = (unsigned char*)d_ws;
    size_t off = 0;
    unsigned short* Wq = (unsigned short*)(base + off); off += 221184;
    unsigned short* Vb = (unsigned short*)(base + off); off += 393216;
    float* P  = (float*)(base + off); off += 442368;
    float* ST = (float*)(base + off); off += 4608;
    float2* PS = (float2*)(base + off); off += 520704;    // 576*113*8
    unsigned char* big = base + off;
    size_t nS2 = (size_t)BS * AN * HW * 2;                // 16,588,800
    size_t xtpBytes = (size_t)BS * 24 * XROWS * XCOLS * 16;  // 98,942,976
    unsigned short* S1b = (unsigned short*)big;
    unsigned short* S2n = (unsigned short*)(big + nS2);
    unsigned short* AMb = (unsigned short*)(big + 2 * nS2);
    off += xtpBytes;                                      // big region reservation
    size_t k1bBytes = (size_t)BS * C * HW * 2;            // 88,473,600
    unsigned short* k1b = nullptr;
    unsigned short* xTp = (unsigned short*)big;           // fallback alias
    int xtpSep = 0;
    if (ws_size >= off + k1bBytes) {
        k1b = (unsigned short*)(base + off); off += k1bBytes;
        if (ws_size >= off + xtpBytes) {
            xTp = (unsigned short*)(base + off); off += xtpBytes;
            xtpSep = 1;
        }
    }
    int writeF32 = (k1b == nullptr) ? 1 : 0;

    k_wfold<<<(NWQ + 255) / 256, 256, 0, stream>>>(key_w, bn1_g, bn1_v, Wq);
    k_xt<<<dim3(H, BS), 256, 0, stream>>>(x, xTp);
    k_pool_b<<<dim3(24, BS), 256, 0, stream>>>(xTp, P);
    k_val<<<BS, 256, 0, stream>>>(val_w, P, Vb);
    k_conv_mfma<<<dim3(H / 2, 3, BS), 256, 0, stream>>>(
        xTp, Wq, bn1_g, bn1_b, bn1_m, bn1_v, out, k1b, writeF32);
    k_scores_mfma<<<dim3(NBLK, BS), 256, 0, stream>>>(
        P, out, k1b, x, xtpSep ? xTp : nullptr, S1b, S2n, PS);
    k_redstats<<<BS * AN, 128, 0, stream>>>(PS, ST);
    k_fuse<<<dim3((HW + 255) / 256, BS), 256, 0, stream>>>(
        S1b, ST, S2n, att_w1, bn2_g, bn2_b, bn2_m, bn2_v, att_w2, att_b2, AMb);
    k_out_mfma<<<dim3(HW / OPX, BS), 256, 0, stream>>>(AMb, Vb, k1b, out);
}